// Round 1
// baseline (736.037 us; speedup 1.0000x reference)
//
#include <hip/hip_runtime.h>
#include <hip/hip_bf16.h>
#include <cstdint>
#include <cstddef>

#define D_IN 128
#define D_H  128
#define D_OUT 64
#define BN_EPS 1e-5f

// ---------------- init: zero histogram, stats, total counter ----------------
__global__ void init_kernel(int* __restrict__ count, int* __restrict__ gtotal,
                            float* __restrict__ stats1, float* __restrict__ stats2, int n) {
    int i = blockIdx.x * blockDim.x + threadIdx.x;
    if (i < n) count[i] = 0;
    if (i < 256) { stats1[i] = 0.f; stats2[i] = 0.f; }
    if (i == 0) *gtotal = 0;
}

// ---------------- histogram of dst ----------------
__global__ void count_kernel(const int* __restrict__ ei, int* __restrict__ count, int e) {
    int i = blockIdx.x * blockDim.x + threadIdx.x;
    if (i < e) atomicAdd(&count[ei[e + i]], 1);
}

// ---------------- dinv + row offsets (wave scan + bump allocator) ----------------
__global__ void offsets_kernel(const int* __restrict__ count, float* __restrict__ dinv,
                               int* __restrict__ rowstart, int* __restrict__ cursor,
                               int* __restrict__ gtotal, int n) {
    int i = blockIdx.x * blockDim.x + threadIdx.x;
    int lane = threadIdx.x & 63;
    int v = (i < n) ? count[i] : 0;
    if (i < n) dinv[i] = rsqrtf((float)v + 1.0f);   // deg = indeg + self loop
    // wave-inclusive scan
    int x = v;
    #pragma unroll
    for (int off = 1; off < 64; off <<= 1) {
        int y = __shfl_up(x, off);
        if (lane >= off) x += y;
    }
    int total = __shfl(x, 63);
    int base = 0;
    if (lane == 63) base = atomicAdd(gtotal, total);
    base = __shfl(base, 63);
    int excl = x - v;
    if (i < n) { rowstart[i] = base + excl; cursor[i] = base + excl; }
}

// ---------------- scatter edges into CSR ----------------
__global__ void scatter_kernel(const int* __restrict__ ei, int* __restrict__ cursor,
                               int* __restrict__ srcs, int e) {
    int i = blockIdx.x * blockDim.x + threadIdx.x;
    if (i < e) {
        int d = ei[e + i];
        int pos = atomicAdd(&cursor[d], 1);
        srcs[pos] = ei[i];
    }
}

// ---------------- GCN propagation: one wave per node, gather over CSR ----------------
__global__ void prop_kernel(const float* __restrict__ in, float* __restrict__ out,
                            const float* __restrict__ dinv,
                            const int* __restrict__ rowstart, const int* __restrict__ cnt,
                            const int* __restrict__ srcs, int n) {
    int wid = (blockIdx.x * blockDim.x + threadIdx.x) >> 6;
    int lane = threadIdx.x & 63;
    if (wid >= n) return;
    int d = wid;
    float di = dinv[d];
    float2 acc = *reinterpret_cast<const float2*>(in + (size_t)d * 128 + lane * 2);
    float wself = di * di;
    acc.x *= wself; acc.y *= wself;
    int beg = rowstart[d];
    int len = cnt[d];
    for (int t = 0; t < len; ++t) {
        int s = srcs[beg + t];
        float w = dinv[s] * di;
        float2 v = *reinterpret_cast<const float2*>(in + (size_t)s * 128 + lane * 2);
        acc.x = fmaf(v.x, w, acc.x);
        acc.y = fmaf(v.y, w, acc.y);
    }
    *reinterpret_cast<float2*>(out + (size_t)d * 128 + lane * 2) = acc;
}

// ---------------- row-transform GEMM: [n,128] @ [128,COLS] + b, optional BN stats ----------------
template <int COLS, bool STATS>
__global__ __launch_bounds__(256) void gemm_kernel(const float* __restrict__ in,
                                                   const float* __restrict__ W,
                                                   const float* __restrict__ bias,
                                                   float* __restrict__ out,
                                                   float* __restrict__ stats, int n) {
    constexpr int CG = COLS / 8;     // column groups of 8
    constexpr int RG = 256 / CG;     // row groups
    constexpr int RPT = 64 / RG;     // rows per thread
    __shared__ float Wl[32 * COLS];  // k-chunk of W
    __shared__ float inl[64][129];   // input tile, padded
    __shared__ float s_sum[COLS];
    __shared__ float s_sq[COLS];

    int t = threadIdx.x;
    int row0 = blockIdx.x * 64;
    int rows = min(64, n - row0);

    for (int i = t * 4; i < 64 * 128; i += 1024) {
        int r = i >> 7, c = i & 127;
        if (r < rows) {
            float4 v = *reinterpret_cast<const float4*>(in + (size_t)(row0 + r) * 128 + c);
            inl[r][c] = v.x; inl[r][c + 1] = v.y; inl[r][c + 2] = v.z; inl[r][c + 3] = v.w;
        }
    }
    if (STATS) {
        for (int i = t; i < COLS; i += 256) { s_sum[i] = 0.f; s_sq[i] = 0.f; }
    }

    int cg = t % CG, rg = t / CG;
    int cb = cg * 8;
    int r0 = rg * RPT;
    float acc[RPT][8];
    #pragma unroll
    for (int r = 0; r < RPT; ++r)
        #pragma unroll
        for (int j = 0; j < 8; ++j) acc[r][j] = bias[cb + j];

    for (int kb = 0; kb < 128; kb += 32) {
        __syncthreads();
        for (int i = t * 4; i < 32 * COLS; i += 1024)
            *reinterpret_cast<float4*>(&Wl[i]) =
                *reinterpret_cast<const float4*>(W + (size_t)kb * COLS + i);
        __syncthreads();
        #pragma unroll 8
        for (int k = 0; k < 32; ++k) {
            float4 wa = *reinterpret_cast<const float4*>(&Wl[k * COLS + cb]);
            float4 wb = *reinterpret_cast<const float4*>(&Wl[k * COLS + cb + 4]);
            #pragma unroll
            for (int r = 0; r < RPT; ++r) {
                float a = inl[r0 + r][kb + k];
                acc[r][0] = fmaf(a, wa.x, acc[r][0]);
                acc[r][1] = fmaf(a, wa.y, acc[r][1]);
                acc[r][2] = fmaf(a, wa.z, acc[r][2]);
                acc[r][3] = fmaf(a, wa.w, acc[r][3]);
                acc[r][4] = fmaf(a, wb.x, acc[r][4]);
                acc[r][5] = fmaf(a, wb.y, acc[r][5]);
                acc[r][6] = fmaf(a, wb.z, acc[r][6]);
                acc[r][7] = fmaf(a, wb.w, acc[r][7]);
            }
        }
    }

    #pragma unroll
    for (int r = 0; r < RPT; ++r) {
        int row = row0 + r0 + r;
        if (row < n) {
            float* o = out + (size_t)row * COLS + cb;
            *reinterpret_cast<float4*>(o)     = make_float4(acc[r][0], acc[r][1], acc[r][2], acc[r][3]);
            *reinterpret_cast<float4*>(o + 4) = make_float4(acc[r][4], acc[r][5], acc[r][6], acc[r][7]);
        }
    }

    if (STATS) {
        float ps[8], pq[8];
        #pragma unroll
        for (int j = 0; j < 8; ++j) { ps[j] = 0.f; pq[j] = 0.f; }
        #pragma unroll
        for (int r = 0; r < RPT; ++r) {
            if (row0 + r0 + r < n) {
                #pragma unroll
                for (int j = 0; j < 8; ++j) {
                    float v = acc[r][j];
                    ps[j] += v; pq[j] += v * v;
                }
            }
        }
        #pragma unroll
        for (int j = 0; j < 8; ++j) {
            atomicAdd(&s_sum[cb + j], ps[j]);
            atomicAdd(&s_sq[cb + j], pq[j]);
        }
        __syncthreads();
        if (t < COLS) {
            atomicAdd(&stats[t], s_sum[t]);
            atomicAdd(&stats[COLS + t], s_sq[t]);
        }
    }
}

// ---------------- BN coefficients ----------------
__global__ void coef_kernel(const float* __restrict__ stats, const float* __restrict__ g,
                            const float* __restrict__ be, float* __restrict__ coef, int n) {
    int j = threadIdx.x;
    if (j < 128) {
        float inv_n = 1.0f / (float)n;
        float mean = stats[j] * inv_n;
        float var = stats[128 + j] * inv_n - mean * mean;
        float a = g[j] * rsqrtf(var + BN_EPS);
        coef[j] = a;
        coef[128 + j] = be[j] - mean * a;
    }
}

// ---------------- BN + ReLU elementwise (in place) ----------------
__global__ void bnrelu_kernel(float* __restrict__ y, const float* __restrict__ coef, int total4) {
    int i = blockIdx.x * blockDim.x + threadIdx.x;
    if (i < total4) {
        float4 v = reinterpret_cast<float4*>(y)[i];
        int c = (i * 4) & 127;
        v.x = fmaxf(fmaf(v.x, coef[c + 0], coef[128 + c + 0]), 0.f);
        v.y = fmaxf(fmaf(v.y, coef[c + 1], coef[128 + c + 1]), 0.f);
        v.z = fmaxf(fmaf(v.z, coef[c + 2], coef[128 + c + 2]), 0.f);
        v.w = fmaxf(fmaf(v.w, coef[c + 3], coef[128 + c + 3]), 0.f);
        reinterpret_cast<float4*>(y)[i] = v;
    }
}

// ---------------- decode: sigmoid(dot(emb[a], emb[b])) ----------------
__global__ void decode_kernel(const float* __restrict__ emb, const int* __restrict__ lab,
                              float* __restrict__ r, int elab) {
    int wid = (blockIdx.x * blockDim.x + threadIdx.x) >> 6;
    int lane = threadIdx.x & 63;
    if (wid >= elab) return;
    int a = lab[wid], b = lab[elab + wid];
    float2 va = *reinterpret_cast<const float2*>(emb + (size_t)a * 128 + lane * 2);
    float2 vb = *reinterpret_cast<const float2*>(emb + (size_t)b * 128 + lane * 2);
    float s = va.x * vb.x + va.y * vb.y;
    #pragma unroll
    for (int off = 32; off > 0; off >>= 1) s += __shfl_down(s, off);
    if (lane == 0) r[wid] = 1.0f / (1.0f + expf(-s));
}

static inline char* carve(char*& p, size_t bytes) {
    char* r = p;
    p += (bytes + 255) & ~(size_t)255;
    return r;
}

extern "C" void kernel_launch(void* const* d_in, const int* in_sizes, int n_in,
                              void* d_out, int out_size, void* d_ws, size_t ws_size,
                              hipStream_t stream) {
    const float* x   = (const float*)d_in[0];
    const int*   ei  = (const int*)d_in[1];
    const int*   lab = (const int*)d_in[2];
    const float* W1 = (const float*)d_in[3],  *b1 = (const float*)d_in[4];
    const float* g1 = (const float*)d_in[5],  *be1 = (const float*)d_in[6];
    const float* W2 = (const float*)d_in[7],  *b2 = (const float*)d_in[8];
    const float* g2 = (const float*)d_in[9],  *be2 = (const float*)d_in[10];
    const float* W3 = (const float*)d_in[11], *b3 = (const float*)d_in[12];

    const int N = in_sizes[0] / 128;
    const int E = in_sizes[1] / 2;
    const int ELAB = in_sizes[2] / 2;

    char* p = (char*)d_ws;
    int*   count    = (int*)carve(p, (size_t)N * 4);
    int*   cursor   = (int*)carve(p, (size_t)N * 4);
    int*   rowstart = (int*)carve(p, (size_t)N * 4);
    float* dinv     = (float*)carve(p, (size_t)N * 4);
    int*   srcs     = (int*)carve(p, (size_t)E * 4);
    int*   gtotal   = (int*)carve(p, 256);
    float* stats1   = (float*)carve(p, 256 * 4);
    float* stats2   = (float*)carve(p, 256 * 4);
    float* coef1    = (float*)carve(p, 256 * 4);
    float* coef2    = (float*)carve(p, 256 * 4);
    float* bufA     = (float*)carve(p, (size_t)N * 128 * 4);
    float* bufB     = (float*)carve(p, (size_t)N * 128 * 4);

    dim3 blk(256);
    int gN   = (N + 255) / 256;
    int gE   = (E + 255) / 256;
    int gWN  = (N * 64 + 255) / 256;   // one wave per node
    int gWL  = (ELAB * 64 + 255) / 256;
    int gG   = (N + 63) / 64;
    int g4   = (N * 32 + 255) / 256;   // float4 elementwise

    // build CSR
    init_kernel<<<gN, blk, 0, stream>>>(count, gtotal, stats1, stats2, N);
    count_kernel<<<gE, blk, 0, stream>>>(ei, count, E);
    offsets_kernel<<<gN, blk, 0, stream>>>(count, dinv, rowstart, cursor, gtotal, N);
    scatter_kernel<<<gE, blk, 0, stream>>>(ei, cursor, srcs, E);

    // layer 1
    prop_kernel<<<gWN, blk, 0, stream>>>(x, bufA, dinv, rowstart, count, srcs, N);
    gemm_kernel<128, true><<<gG, blk, 0, stream>>>(bufA, W1, b1, bufB, stats1, N);
    coef_kernel<<<1, 128, 0, stream>>>(stats1, g1, be1, coef1, N);
    bnrelu_kernel<<<g4, blk, 0, stream>>>(bufB, coef1, N * 32);

    // layer 2
    prop_kernel<<<gWN, blk, 0, stream>>>(bufB, bufA, dinv, rowstart, count, srcs, N);
    gemm_kernel<128, true><<<gG, blk, 0, stream>>>(bufA, W2, b2, bufB, stats2, N);
    coef_kernel<<<1, 128, 0, stream>>>(stats2, g2, be2, coef2, N);
    bnrelu_kernel<<<g4, blk, 0, stream>>>(bufB, coef2, N * 32);

    // layer 3: emb = prop(h2); x_out = emb @ W3 + b3; r = sigmoid(<emb,emb>)
    prop_kernel<<<gWN, blk, 0, stream>>>(bufB, bufA, dinv, rowstart, count, srcs, N);
    gemm_kernel<64, false><<<gG, blk, 0, stream>>>(bufA, W3, b3, (float*)d_out, nullptr, N);
    decode_kernel<<<gWL, blk, 0, stream>>>(bufA, lab, (float*)d_out + (size_t)N * 64, ELAB);
}

// Round 2
// 633.045 us; speedup vs baseline: 1.1627x; 1.1627x over previous
//
#include <hip/hip_runtime.h>
#include <hip/hip_bf16.h>
#include <cstdint>
#include <cstddef>

#define BN_EPS 1e-5f

// ---------------- init: zero histogram, stats, total counter ----------------
__global__ void init_kernel(int* __restrict__ count, int* __restrict__ gtotal,
                            float* __restrict__ stats1, float* __restrict__ stats2, int n) {
    int i = blockIdx.x * blockDim.x + threadIdx.x;
    if (i < n) count[i] = 0;
    if (i < 256) { stats1[i] = 0.f; stats2[i] = 0.f; }
    if (i == 0) *gtotal = 0;
}

// ---------------- histogram of dst ----------------
__global__ void count_kernel(const int* __restrict__ ei, int* __restrict__ count, int e) {
    int i = blockIdx.x * blockDim.x + threadIdx.x;
    if (i < e) atomicAdd(&count[ei[e + i]], 1);
}

// ---------------- dinv + row offsets (wave scan + bump allocator) ----------------
__global__ void offsets_kernel(const int* __restrict__ count, float* __restrict__ dinv,
                               int* __restrict__ rowstart, int* __restrict__ cursor,
                               int* __restrict__ gtotal, int n) {
    int i = blockIdx.x * blockDim.x + threadIdx.x;
    int lane = threadIdx.x & 63;
    int v = (i < n) ? count[i] : 0;
    if (i < n) dinv[i] = rsqrtf((float)v + 1.0f);   // deg = indeg + self loop
    int x = v;
    #pragma unroll
    for (int off = 1; off < 64; off <<= 1) {
        int y = __shfl_up(x, off);
        if (lane >= off) x += y;
    }
    int total = __shfl(x, 63);
    int base = 0;
    if (lane == 63) base = atomicAdd(gtotal, total);
    base = __shfl(base, 63);
    int excl = x - v;
    if (i < n) { rowstart[i] = base + excl; cursor[i] = base + excl; }
}

// ---------------- scatter edges into CSR with precomputed weight ----------------
__global__ void scatter_kernel(const int* __restrict__ ei, int* __restrict__ cursor,
                               const float* __restrict__ dinv,
                               int2* __restrict__ edges, int e) {
    int i = blockIdx.x * blockDim.x + threadIdx.x;
    if (i < e) {
        int d = ei[e + i];
        int s = ei[i];
        int pos = atomicAdd(&cursor[d], 1);
        float w = dinv[s] * dinv[d];
        edges[pos] = make_int2(s, __float_as_int(w));
    }
}

// ---------------- GCN propagation: one wave per node, gather over CSR ----------------
// BN=true applies y = relu(v*ca + cb) to each gathered source row (fused BN+ReLU).
template <bool BN>
__global__ __launch_bounds__(256) void prop_kernel(
        const float* __restrict__ in, float* __restrict__ out,
        const float* __restrict__ coef,
        const float* __restrict__ dinv, const int* __restrict__ rowstart,
        const int* __restrict__ cnt, const int2* __restrict__ edges, int n) {
    int wid = (blockIdx.x * blockDim.x + threadIdx.x) >> 6;
    int lane = threadIdx.x & 63;
    if (wid >= n) return;
    int c0 = lane * 2;
    float2 ca, cb;
    if (BN) {
        ca = *reinterpret_cast<const float2*>(coef + c0);
        cb = *reinterpret_cast<const float2*>(coef + 128 + c0);
    }
    float di = dinv[wid];
    float2 v = *reinterpret_cast<const float2*>(in + (size_t)wid * 128 + c0);
    if (BN) {
        v.x = fmaxf(fmaf(v.x, ca.x, cb.x), 0.f);
        v.y = fmaxf(fmaf(v.y, ca.y, cb.y), 0.f);
    }
    float ws = di * di;
    float2 acc = make_float2(v.x * ws, v.y * ws);
    int beg = rowstart[wid], len = cnt[wid];
    int t = 0;
    for (; t + 2 <= len; t += 2) {
        int2 e0 = edges[beg + t];
        int2 e1 = edges[beg + t + 1];
        float2 v0 = *reinterpret_cast<const float2*>(in + (size_t)e0.x * 128 + c0);
        float2 v1 = *reinterpret_cast<const float2*>(in + (size_t)e1.x * 128 + c0);
        float w0 = __int_as_float(e0.y), w1 = __int_as_float(e1.y);
        if (BN) {
            v0.x = fmaxf(fmaf(v0.x, ca.x, cb.x), 0.f);
            v0.y = fmaxf(fmaf(v0.y, ca.y, cb.y), 0.f);
            v1.x = fmaxf(fmaf(v1.x, ca.x, cb.x), 0.f);
            v1.y = fmaxf(fmaf(v1.y, ca.y, cb.y), 0.f);
        }
        acc.x = fmaf(v0.x, w0, acc.x);
        acc.y = fmaf(v0.y, w0, acc.y);
        acc.x = fmaf(v1.x, w1, acc.x);
        acc.y = fmaf(v1.y, w1, acc.y);
    }
    if (t < len) {
        int2 e0 = edges[beg + t];
        float2 v0 = *reinterpret_cast<const float2*>(in + (size_t)e0.x * 128 + c0);
        float w0 = __int_as_float(e0.y);
        if (BN) {
            v0.x = fmaxf(fmaf(v0.x, ca.x, cb.x), 0.f);
            v0.y = fmaxf(fmaf(v0.y, ca.y, cb.y), 0.f);
        }
        acc.x = fmaf(v0.x, w0, acc.x);
        acc.y = fmaf(v0.y, w0, acc.y);
    }
    *reinterpret_cast<float2*>(out + (size_t)wid * 128 + c0) = acc;
}

// ---------------- GEMM: [n,128] @ [128,COLS] + b, optional BN stats ----------------
// 128 rows per block, 256 threads, per-thread tile RPT x 8.
// W chunk (32 k) staged in LDS as two float4 arrays (bank-conflict-free);
// A read directly from global (each element touched once per block, 4-row
// broadcast per instruction) -- keeps the LDS pipe half-loaded.
template <int COLS, bool STATS>
__global__ __launch_bounds__(256, 2) void gemm_kernel(
        const float* __restrict__ in, const float* __restrict__ W,
        const float* __restrict__ bias, float* __restrict__ out,
        float* __restrict__ stats, int n) {
    constexpr int CG = COLS / 8;      // 16 (COLS=128) or 8 (COLS=64)
    constexpr int RG = 256 / CG;      // 16 or 32
    constexpr int RPT = 128 / RG;     // 8 or 4 rows per thread
    __shared__ float4 WlA[32 * CG];
    __shared__ float4 WlB[32 * CG];
    __shared__ float s_sum[COLS];
    __shared__ float s_sq[COLS];

    int t = threadIdx.x;
    int cg = t % CG, rg = t / CG;
    int cb = cg * 8;
    int row0 = blockIdx.x * 128 + rg * RPT;

    if (STATS) {
        for (int i = t; i < COLS; i += 256) { s_sum[i] = 0.f; s_sq[i] = 0.f; }
    }

    const float* arow[RPT];
    #pragma unroll
    for (int r = 0; r < RPT; ++r) {
        int row = row0 + r;
        arow[r] = in + (size_t)min(row, n - 1) * 128;
    }

    float acc[RPT][8];
    #pragma unroll
    for (int r = 0; r < RPT; ++r) {
        #pragma unroll
        for (int j = 0; j < 8; ++j) acc[r][j] = 0.f;
    }

    for (int kb = 0; kb < 4; ++kb) {
        __syncthreads();
        for (int idx = t; idx < 32 * COLS / 4; idx += 256) {
            int k = idx / (COLS / 4), c4 = idx % (COLS / 4);
            float4 v = *reinterpret_cast<const float4*>(W + (size_t)(kb * 32 + k) * COLS + c4 * 4);
            int cgi = c4 >> 1;
            if (c4 & 1) WlB[k * CG + cgi] = v; else WlA[k * CG + cgi] = v;
        }
        __syncthreads();
        #pragma unroll
        for (int k4 = 0; k4 < 8; ++k4) {
            float4 a[RPT];
            #pragma unroll
            for (int r = 0; r < RPT; ++r)
                a[r] = *reinterpret_cast<const float4*>(arow[r] + kb * 32 + k4 * 4);
            float4 wa[4], wb[4];
            #pragma unroll
            for (int kk = 0; kk < 4; ++kk) {
                wa[kk] = WlA[(k4 * 4 + kk) * CG + cg];
                wb[kk] = WlB[(k4 * 4 + kk) * CG + cg];
            }
            #pragma unroll
            for (int kk = 0; kk < 4; ++kk) {
                #pragma unroll
                for (int r = 0; r < RPT; ++r) {
                    float av = (kk == 0) ? a[r].x : (kk == 1) ? a[r].y : (kk == 2) ? a[r].z : a[r].w;
                    acc[r][0] = fmaf(av, wa[kk].x, acc[r][0]);
                    acc[r][1] = fmaf(av, wa[kk].y, acc[r][1]);
                    acc[r][2] = fmaf(av, wa[kk].z, acc[r][2]);
                    acc[r][3] = fmaf(av, wa[kk].w, acc[r][3]);
                    acc[r][4] = fmaf(av, wb[kk].x, acc[r][4]);
                    acc[r][5] = fmaf(av, wb[kk].y, acc[r][5]);
                    acc[r][6] = fmaf(av, wb[kk].z, acc[r][6]);
                    acc[r][7] = fmaf(av, wb[kk].w, acc[r][7]);
                }
            }
        }
    }

    // bias + store
    #pragma unroll
    for (int r = 0; r < RPT; ++r) {
        int row = row0 + r;
        if (row < n) {
            float4 o0 = make_float4(acc[r][0] + bias[cb + 0], acc[r][1] + bias[cb + 1],
                                    acc[r][2] + bias[cb + 2], acc[r][3] + bias[cb + 3]);
            float4 o1 = make_float4(acc[r][4] + bias[cb + 4], acc[r][5] + bias[cb + 5],
                                    acc[r][6] + bias[cb + 6], acc[r][7] + bias[cb + 7]);
            float* o = out + (size_t)row * COLS + cb;
            *reinterpret_cast<float4*>(o) = o0;
            *reinterpret_cast<float4*>(o + 4) = o1;
        }
    }

    if (STATS) {
        float ps[8], pq[8];
        #pragma unroll
        for (int j = 0; j < 8; ++j) { ps[j] = 0.f; pq[j] = 0.f; }
        #pragma unroll
        for (int r = 0; r < RPT; ++r) {
            if (row0 + r < n) {
                #pragma unroll
                for (int j = 0; j < 8; ++j) {
                    float v = acc[r][j] + bias[cb + j];
                    ps[j] += v; pq[j] += v * v;
                }
            }
        }
        #pragma unroll
        for (int j = 0; j < 8; ++j) {
            atomicAdd(&s_sum[cb + j], ps[j]);
            atomicAdd(&s_sq[cb + j], pq[j]);
        }
        __syncthreads();
        if (t < COLS) {
            atomicAdd(&stats[t], s_sum[t]);
            atomicAdd(&stats[COLS + t], s_sq[t]);
        }
    }
}

// ---------------- BN coefficients ----------------
__global__ void coef_kernel(const float* __restrict__ stats, const float* __restrict__ g,
                            const float* __restrict__ be, float* __restrict__ coef, int n) {
    int j = threadIdx.x;
    if (j < 128) {
        float inv_n = 1.0f / (float)n;
        float mean = stats[j] * inv_n;
        float var = stats[128 + j] * inv_n - mean * mean;
        float a = g[j] * rsqrtf(var + BN_EPS);
        coef[j] = a;
        coef[128 + j] = be[j] - mean * a;
    }
}

// ---------------- decode: sigmoid(dot(emb[a], emb[b])) ----------------
__global__ void decode_kernel(const float* __restrict__ emb, const int* __restrict__ lab,
                              float* __restrict__ r, int elab) {
    int wid = (blockIdx.x * blockDim.x + threadIdx.x) >> 6;
    int lane = threadIdx.x & 63;
    if (wid >= elab) return;
    int a = lab[wid], b = lab[elab + wid];
    float2 va = *reinterpret_cast<const float2*>(emb + (size_t)a * 128 + lane * 2);
    float2 vb = *reinterpret_cast<const float2*>(emb + (size_t)b * 128 + lane * 2);
    float s = va.x * vb.x + va.y * vb.y;
    #pragma unroll
    for (int off = 32; off > 0; off >>= 1) s += __shfl_down(s, off);
    if (lane == 0) r[wid] = 1.0f / (1.0f + expf(-s));
}

static inline char* carve(char*& p, size_t bytes) {
    char* r = p;
    p += (bytes + 255) & ~(size_t)255;
    return r;
}

extern "C" void kernel_launch(void* const* d_in, const int* in_sizes, int n_in,
                              void* d_out, int out_size, void* d_ws, size_t ws_size,
                              hipStream_t stream) {
    const float* x   = (const float*)d_in[0];
    const int*   ei  = (const int*)d_in[1];
    const int*   lab = (const int*)d_in[2];
    const float* W1 = (const float*)d_in[3],  *b1 = (const float*)d_in[4];
    const float* g1 = (const float*)d_in[5],  *be1 = (const float*)d_in[6];
    const float* W2 = (const float*)d_in[7],  *b2 = (const float*)d_in[8];
    const float* g2 = (const float*)d_in[9],  *be2 = (const float*)d_in[10];
    const float* W3 = (const float*)d_in[11], *b3 = (const float*)d_in[12];

    const int N = in_sizes[0] / 128;
    const int E = in_sizes[1] / 2;
    const int ELAB = in_sizes[2] / 2;

    char* p = (char*)d_ws;
    int*   count    = (int*)carve(p, (size_t)N * 4);
    int*   cursor   = (int*)carve(p, (size_t)N * 4);
    int*   rowstart = (int*)carve(p, (size_t)N * 4);
    float* dinv     = (float*)carve(p, (size_t)N * 4);
    int2*  edges    = (int2*)carve(p, (size_t)E * 8);
    int*   gtotal   = (int*)carve(p, 256);
    float* stats1   = (float*)carve(p, 256 * 4);
    float* stats2   = (float*)carve(p, 256 * 4);
    float* coef1    = (float*)carve(p, 256 * 4);
    float* coef2    = (float*)carve(p, 256 * 4);
    float* bufA     = (float*)carve(p, (size_t)N * 128 * 4);
    float* bufB     = (float*)carve(p, (size_t)N * 128 * 4);

    dim3 blk(256);
    int gN   = (N + 255) / 256;
    int gE   = (E + 255) / 256;
    int gWN  = (N * 64 + 255) / 256;   // one wave per node
    int gWL  = (ELAB * 64 + 255) / 256;
    int gG   = (N + 127) / 128;

    // build CSR
    init_kernel<<<gN, blk, 0, stream>>>(count, gtotal, stats1, stats2, N);
    count_kernel<<<gE, blk, 0, stream>>>(ei, count, E);
    offsets_kernel<<<gN, blk, 0, stream>>>(count, dinv, rowstart, cursor, gtotal, N);
    scatter_kernel<<<gE, blk, 0, stream>>>(ei, cursor, dinv, edges, E);

    // layer 1
    prop_kernel<false><<<gWN, blk, 0, stream>>>(x, bufA, nullptr, dinv, rowstart, count, edges, N);
    gemm_kernel<128, true><<<gG, blk, 0, stream>>>(bufA, W1, b1, bufB, stats1, N);
    coef_kernel<<<1, 128, 0, stream>>>(stats1, g1, be1, coef1, N);

    // layer 2 (BN+ReLU of layer 1 fused into prop's read path)
    prop_kernel<true><<<gWN, blk, 0, stream>>>(bufB, bufA, coef1, dinv, rowstart, count, edges, N);
    gemm_kernel<128, true><<<gG, blk, 0, stream>>>(bufA, W2, b2, bufB, stats2, N);
    coef_kernel<<<1, 128, 0, stream>>>(stats2, g2, be2, coef2, N);

    // layer 3: emb = prop(relu(bn(h2))); x_out = emb @ W3 + b3; r = sigmoid(<emb,emb>)
    prop_kernel<true><<<gWN, blk, 0, stream>>>(bufB, bufA, coef2, dinv, rowstart, count, edges, N);
    gemm_kernel<64, false><<<gG, blk, 0, stream>>>(bufA, W3, b3, (float*)d_out, nullptr, N);
    decode_kernel<<<gWL, blk, 0, stream>>>(bufA, lab, (float*)d_out + (size_t)N * 64, ELAB);
}

// Round 3
// 475.455 us; speedup vs baseline: 1.5481x; 1.3315x over previous
//
#include <hip/hip_runtime.h>
#include <hip/hip_bf16.h>
#include <cstdint>
#include <cstddef>

#define BN_EPS 1e-5f

typedef float f32x4 __attribute__((ext_vector_type(4)));
typedef __bf16 bf16x8 __attribute__((ext_vector_type(8)));

__device__ __forceinline__ unsigned short f2b(float f) {
    unsigned int x = __builtin_bit_cast(unsigned int, f);
    x += 0x7fffu + ((x >> 16) & 1u);          // RNE
    return (unsigned short)(x >> 16);
}
__device__ __forceinline__ float b2f(unsigned short u) {
    return __builtin_bit_cast(float, (unsigned int)u << 16);
}

// ---------------- init: zero histogram, stats, total counter ----------------
__global__ void init_kernel(int* __restrict__ count, int* __restrict__ gtotal,
                            float* __restrict__ stats1, float* __restrict__ stats2, int n) {
    int i = blockIdx.x * blockDim.x + threadIdx.x;
    if (i < n) count[i] = 0;
    if (i < 256) { stats1[i] = 0.f; stats2[i] = 0.f; }
    if (i == 0) *gtotal = 0;
}

// ---------------- histogram of dst ----------------
__global__ void count_kernel(const int* __restrict__ ei, int* __restrict__ count, int e) {
    int i = blockIdx.x * blockDim.x + threadIdx.x;
    if (i < e) atomicAdd(&count[ei[e + i]], 1);
}

// ---------------- dinv + row offsets (wave scan + bump allocator) ----------------
__global__ void offsets_kernel(const int* __restrict__ count, float* __restrict__ dinv,
                               int* __restrict__ rowstart, int* __restrict__ cursor,
                               int* __restrict__ gtotal, int n) {
    int i = blockIdx.x * blockDim.x + threadIdx.x;
    int lane = threadIdx.x & 63;
    int v = (i < n) ? count[i] : 0;
    if (i < n) dinv[i] = rsqrtf((float)v + 1.0f);   // deg = indeg + self loop
    int x = v;
    #pragma unroll
    for (int off = 1; off < 64; off <<= 1) {
        int y = __shfl_up(x, off);
        if (lane >= off) x += y;
    }
    int total = __shfl(x, 63);
    int base = 0;
    if (lane == 63) base = atomicAdd(gtotal, total);
    base = __shfl(base, 63);
    int excl = x - v;
    if (i < n) { rowstart[i] = base + excl; cursor[i] = base + excl; }
}

// ---------------- scatter edges into CSR with precomputed weight ----------------
__global__ void scatter_kernel(const int* __restrict__ ei, int* __restrict__ cursor,
                               const float* __restrict__ dinv,
                               int2* __restrict__ edges, int e) {
    int i = blockIdx.x * blockDim.x + threadIdx.x;
    if (i < e) {
        int d = ei[e + i];
        int s = ei[i];
        int pos = atomicAdd(&cursor[d], 1);
        float w = dinv[s] * dinv[d];
        edges[pos] = make_int2(s, __float_as_int(w));
    }
}

// ---------------- f32 -> bf16 convert ----------------
__global__ void cvt_kernel(const float* __restrict__ in, unsigned short* __restrict__ out, int n4) {
    int i = blockIdx.x * blockDim.x + threadIdx.x;
    if (i < n4) {
        float4 v = reinterpret_cast<const float4*>(in)[i];
        ushort4 o;
        o.x = f2b(v.x); o.y = f2b(v.y); o.z = f2b(v.z); o.w = f2b(v.w);
        reinterpret_cast<ushort4*>(out)[i] = o;
    }
}

// ---------------- W prep: transpose + bf16 + XOR-swizzle for LDS b128 reads ----------
// out layout: value W[k][c] at ushort index c*128 + ((k>>3)^(c&7))*8 + (k&7)
__global__ void wprep_kernel(const float* __restrict__ W, unsigned short* __restrict__ out, int cols) {
    int i = blockIdx.x * blockDim.x + threadIdx.x;
    if (i >= 128 * cols) return;
    int k = i / cols, c = i % cols;
    int chunk = (k >> 3) ^ (c & 7);
    out[c * 128 + chunk * 8 + (k & 7)] = f2b(W[i]);
}

// ---------------- GCN propagation: one wave per node, gather over CSR (bf16) ----------
// BN=true applies y = relu(v*ca + cb) to each gathered source row (fused BN+ReLU).
template <bool BN>
__global__ __launch_bounds__(256) void prop_kernel(
        const unsigned short* __restrict__ in, unsigned short* __restrict__ out,
        const float* __restrict__ coef,
        const float* __restrict__ dinv, const int* __restrict__ rowstart,
        const int* __restrict__ cnt, const int2* __restrict__ edges, int n) {
    int wid = (blockIdx.x * blockDim.x + threadIdx.x) >> 6;
    int lane = threadIdx.x & 63;
    if (wid >= n) return;
    int c0 = lane * 2;
    float ca0 = 0.f, ca1 = 0.f, cb0 = 0.f, cb1 = 0.f;
    if (BN) {
        ca0 = coef[c0]; ca1 = coef[c0 + 1];
        cb0 = coef[128 + c0]; cb1 = coef[128 + c0 + 1];
    }
    float di = dinv[wid];
    ushort2 sv = *reinterpret_cast<const ushort2*>(in + (size_t)wid * 128 + c0);
    float vx = b2f(sv.x), vy = b2f(sv.y);
    if (BN) {
        vx = fmaxf(fmaf(vx, ca0, cb0), 0.f);
        vy = fmaxf(fmaf(vy, ca1, cb1), 0.f);
    }
    float ws = di * di;
    float ax = vx * ws, ay = vy * ws;
    int beg = rowstart[wid], len = cnt[wid];
    int t = 0;
    for (; t + 4 <= len; t += 4) {
        int2 e0 = edges[beg + t], e1 = edges[beg + t + 1];
        int2 e2 = edges[beg + t + 2], e3 = edges[beg + t + 3];
        ushort2 u0 = *reinterpret_cast<const ushort2*>(in + (size_t)e0.x * 128 + c0);
        ushort2 u1 = *reinterpret_cast<const ushort2*>(in + (size_t)e1.x * 128 + c0);
        ushort2 u2 = *reinterpret_cast<const ushort2*>(in + (size_t)e2.x * 128 + c0);
        ushort2 u3 = *reinterpret_cast<const ushort2*>(in + (size_t)e3.x * 128 + c0);
        float w0 = __int_as_float(e0.y), w1 = __int_as_float(e1.y);
        float w2 = __int_as_float(e2.y), w3 = __int_as_float(e3.y);
        float x0 = b2f(u0.x), y0 = b2f(u0.y);
        float x1 = b2f(u1.x), y1 = b2f(u1.y);
        float x2 = b2f(u2.x), y2 = b2f(u2.y);
        float x3 = b2f(u3.x), y3 = b2f(u3.y);
        if (BN) {
            x0 = fmaxf(fmaf(x0, ca0, cb0), 0.f); y0 = fmaxf(fmaf(y0, ca1, cb1), 0.f);
            x1 = fmaxf(fmaf(x1, ca0, cb0), 0.f); y1 = fmaxf(fmaf(y1, ca1, cb1), 0.f);
            x2 = fmaxf(fmaf(x2, ca0, cb0), 0.f); y2 = fmaxf(fmaf(y2, ca1, cb1), 0.f);
            x3 = fmaxf(fmaf(x3, ca0, cb0), 0.f); y3 = fmaxf(fmaf(y3, ca1, cb1), 0.f);
        }
        ax = fmaf(x0, w0, ax); ay = fmaf(y0, w0, ay);
        ax = fmaf(x1, w1, ax); ay = fmaf(y1, w1, ay);
        ax = fmaf(x2, w2, ax); ay = fmaf(y2, w2, ay);
        ax = fmaf(x3, w3, ax); ay = fmaf(y3, w3, ay);
    }
    for (; t < len; ++t) {
        int2 e0 = edges[beg + t];
        ushort2 u0 = *reinterpret_cast<const ushort2*>(in + (size_t)e0.x * 128 + c0);
        float w0 = __int_as_float(e0.y);
        float x0 = b2f(u0.x), y0 = b2f(u0.y);
        if (BN) {
            x0 = fmaxf(fmaf(x0, ca0, cb0), 0.f);
            y0 = fmaxf(fmaf(y0, ca1, cb1), 0.f);
        }
        ax = fmaf(x0, w0, ax); ay = fmaf(y0, w0, ay);
    }
    ushort2 o; o.x = f2b(ax); o.y = f2b(ay);
    *reinterpret_cast<ushort2*>(out + (size_t)wid * 128 + c0) = o;
}

// ---------------- MFMA GEMM: bf16 [n,128] @ [128,COLS] + b, optional BN stats --------
// 128 rows/block, 4 waves, each wave 32 rows x COLS.
// B pre-transposed+swizzled in global (wprep), staged linearly into LDS.
template <int COLS, bool OUT_BF, bool STATS>
__global__ __launch_bounds__(256) void gemm_kernel(
        const unsigned short* __restrict__ A, const unsigned short* __restrict__ Bswz,
        const float* __restrict__ bias, void* __restrict__ out,
        float* __restrict__ stats, int n) {
    constexpr int NT = COLS / 16;
    __shared__ unsigned short Blds[128 * COLS];
    __shared__ float s_sum[128];
    __shared__ float s_sq[128];

    int t = threadIdx.x;
    int w = t >> 6, l = t & 63;
    int lr = l & 15, lg = l >> 4;
    int row_base = blockIdx.x * 128 + w * 32;

    // stage swizzled B linearly (conflict-free)
    constexpr int WORDS16 = 128 * COLS * 2 / 16;   // uint4 chunks
    for (int i = t; i < WORDS16; i += 256)
        reinterpret_cast<uint4*>(Blds)[i] = reinterpret_cast<const uint4*>(Bswz)[i];
    if (STATS) {
        for (int i = t; i < COLS; i += 256) { s_sum[i] = 0.f; s_sq[i] = 0.f; }
    }

    // A fragments: row = row_base + m*16 + lr, k = kb*32 + lg*8 + j
    bf16x8 a[2][4];
    #pragma unroll
    for (int m = 0; m < 2; ++m) {
        int row = min(row_base + m * 16 + lr, n - 1);
        const unsigned short* ap = A + (size_t)row * 128 + lg * 8;
        #pragma unroll
        for (int kb = 0; kb < 4; ++kb)
            a[m][kb] = *reinterpret_cast<const bf16x8*>(ap + kb * 32);
    }

    f32x4 acc[2][NT];
    #pragma unroll
    for (int m = 0; m < 2; ++m)
        #pragma unroll
        for (int nn = 0; nn < NT; ++nn)
            acc[m][nn] = f32x4{0.f, 0.f, 0.f, 0.f};

    __syncthreads();

    #pragma unroll
    for (int kb = 0; kb < 4; ++kb) {
        bf16x8 b[NT];
        #pragma unroll
        for (int nn = 0; nn < NT; ++nn) {
            int c = nn * 16 + lr;
            int chunk = (kb * 4 + lg) ^ (c & 7);
            b[nn] = *reinterpret_cast<const bf16x8*>(
                        reinterpret_cast<const char*>(Blds) + c * 256 + chunk * 16);
        }
        #pragma unroll
        for (int m = 0; m < 2; ++m)
            #pragma unroll
            for (int nn = 0; nn < NT; ++nn)
                acc[m][nn] = __builtin_amdgcn_mfma_f32_16x16x32_bf16(a[m][kb], b[nn], acc[m][nn], 0, 0, 0);
    }

    // epilogue: D layout col = lr, row = lg*4 + q
    float ps[NT], pq[NT];
    #pragma unroll
    for (int nn = 0; nn < NT; ++nn) { ps[nn] = 0.f; pq[nn] = 0.f; }
    #pragma unroll
    for (int m = 0; m < 2; ++m) {
        #pragma unroll
        for (int nn = 0; nn < NT; ++nn) {
            int col = nn * 16 + lr;
            float bb = bias[col];
            #pragma unroll
            for (int q = 0; q < 4; ++q) {
                int row = row_base + m * 16 + lg * 4 + q;
                float v = acc[m][nn][q] + bb;
                if (row < n) {
                    if (OUT_BF)
                        reinterpret_cast<unsigned short*>(out)[(size_t)row * COLS + col] = f2b(v);
                    else
                        reinterpret_cast<float*>(out)[(size_t)row * COLS + col] = v;
                    if (STATS) { ps[nn] += v; pq[nn] += v * v; }
                }
            }
        }
    }

    if (STATS) {
        #pragma unroll
        for (int nn = 0; nn < NT; ++nn) {
            atomicAdd(&s_sum[nn * 16 + lr], ps[nn]);
            atomicAdd(&s_sq[nn * 16 + lr], pq[nn]);
        }
        __syncthreads();
        if (t < COLS) {
            atomicAdd(&stats[t], s_sum[t]);
            atomicAdd(&stats[COLS + t], s_sq[t]);
        }
    }
}

// ---------------- BN coefficients ----------------
__global__ void coef_kernel(const float* __restrict__ stats, const float* __restrict__ g,
                            const float* __restrict__ be, float* __restrict__ coef, int n) {
    int j = threadIdx.x;
    if (j < 128) {
        float inv_n = 1.0f / (float)n;
        float mean = stats[j] * inv_n;
        float var = stats[128 + j] * inv_n - mean * mean;
        float a = g[j] * rsqrtf(var + BN_EPS);
        coef[j] = a;
        coef[128 + j] = be[j] - mean * a;
    }
}

// ---------------- decode: sigmoid(dot(emb[a], emb[b])) over bf16 emb ----------------
__global__ void decode_kernel(const unsigned short* __restrict__ emb, const int* __restrict__ lab,
                              float* __restrict__ r, int elab) {
    int wid = (blockIdx.x * blockDim.x + threadIdx.x) >> 6;
    int lane = threadIdx.x & 63;
    if (wid >= elab) return;
    int a = lab[wid], b = lab[elab + wid];
    ushort2 ua = *reinterpret_cast<const ushort2*>(emb + (size_t)a * 128 + lane * 2);
    ushort2 ub = *reinterpret_cast<const ushort2*>(emb + (size_t)b * 128 + lane * 2);
    float s = b2f(ua.x) * b2f(ub.x) + b2f(ua.y) * b2f(ub.y);
    #pragma unroll
    for (int off = 32; off > 0; off >>= 1) s += __shfl_down(s, off);
    if (lane == 0) r[wid] = 1.0f / (1.0f + expf(-s));
}

static inline char* carve(char*& p, size_t bytes) {
    char* r = p;
    p += (bytes + 255) & ~(size_t)255;
    return r;
}

extern "C" void kernel_launch(void* const* d_in, const int* in_sizes, int n_in,
                              void* d_out, int out_size, void* d_ws, size_t ws_size,
                              hipStream_t stream) {
    const float* x   = (const float*)d_in[0];
    const int*   ei  = (const int*)d_in[1];
    const int*   lab = (const int*)d_in[2];
    const float* W1 = (const float*)d_in[3],  *b1 = (const float*)d_in[4];
    const float* g1 = (const float*)d_in[5],  *be1 = (const float*)d_in[6];
    const float* W2 = (const float*)d_in[7],  *b2 = (const float*)d_in[8];
    const float* g2 = (const float*)d_in[9],  *be2 = (const float*)d_in[10];
    const float* W3 = (const float*)d_in[11], *b3 = (const float*)d_in[12];

    const int N = in_sizes[0] / 128;
    const int E = in_sizes[1] / 2;
    const int ELAB = in_sizes[2] / 2;

    char* p = (char*)d_ws;
    int*   count    = (int*)carve(p, (size_t)N * 4);
    int*   cursor   = (int*)carve(p, (size_t)N * 4);
    int*   rowstart = (int*)carve(p, (size_t)N * 4);
    float* dinv     = (float*)carve(p, (size_t)N * 4);
    int2*  edges    = (int2*)carve(p, (size_t)E * 8);
    int*   gtotal   = (int*)carve(p, 256);
    float* stats1   = (float*)carve(p, 256 * 4);
    float* stats2   = (float*)carve(p, 256 * 4);
    float* coef1    = (float*)carve(p, 256 * 4);
    float* coef2    = (float*)carve(p, 256 * 4);
    unsigned short* Wt1 = (unsigned short*)carve(p, 128 * 128 * 2);
    unsigned short* Wt2 = (unsigned short*)carve(p, 128 * 128 * 2);
    unsigned short* Wt3 = (unsigned short*)carve(p, 128 * 64 * 2);
    unsigned short* xb  = (unsigned short*)carve(p, (size_t)N * 128 * 2);
    unsigned short* bA  = (unsigned short*)carve(p, (size_t)N * 128 * 2);
    unsigned short* bB  = (unsigned short*)carve(p, (size_t)N * 128 * 2);

    dim3 blk(256);
    int gN   = (N + 255) / 256;
    int gE   = (E + 255) / 256;
    int gWN  = (N * 64 + 255) / 256;   // one wave per node
    int gWL  = (ELAB * 64 + 255) / 256;
    int gG   = (N + 127) / 128;
    int g4   = (N * 32 + 255) / 256;

    // build CSR + preps
    init_kernel<<<gN, blk, 0, stream>>>(count, gtotal, stats1, stats2, N);
    count_kernel<<<gE, blk, 0, stream>>>(ei, count, E);
    offsets_kernel<<<gN, blk, 0, stream>>>(count, dinv, rowstart, cursor, gtotal, N);
    scatter_kernel<<<gE, blk, 0, stream>>>(ei, cursor, dinv, edges, E);
    cvt_kernel<<<g4, blk, 0, stream>>>(x, xb, N * 32);
    wprep_kernel<<<64, blk, 0, stream>>>(W1, Wt1, 128);
    wprep_kernel<<<64, blk, 0, stream>>>(W2, Wt2, 128);
    wprep_kernel<<<32, blk, 0, stream>>>(W3, Wt3, 64);

    // layer 1
    prop_kernel<false><<<gWN, blk, 0, stream>>>(xb, bA, nullptr, dinv, rowstart, count, edges, N);
    gemm_kernel<128, true, true><<<gG, blk, 0, stream>>>(bA, Wt1, b1, bB, stats1, N);
    coef_kernel<<<1, 128, 0, stream>>>(stats1, g1, be1, coef1, N);

    // layer 2 (BN+ReLU of layer 1 fused into prop's read path)
    prop_kernel<true><<<gWN, blk, 0, stream>>>(bB, bA, coef1, dinv, rowstart, count, edges, N);
    gemm_kernel<128, true, true><<<gG, blk, 0, stream>>>(bA, Wt2, b2, bB, stats2, N);
    coef_kernel<<<1, 128, 0, stream>>>(stats2, g2, be2, coef2, N);

    // layer 3: emb = prop(relu(bn(h2))); x_out = emb @ W3 + b3; r = sigmoid(<emb,emb>)
    prop_kernel<true><<<gWN, blk, 0, stream>>>(bB, bA, coef2, dinv, rowstart, count, edges, N);
    gemm_kernel<64, false, false><<<gG, blk, 0, stream>>>(bA, Wt3, b3, (float*)d_out, nullptr, N);
    decode_kernel<<<gWL, blk, 0, stream>>>(bA, lab, (float*)d_out + (size_t)N * 64, ELAB);
}

// Round 4
// 429.821 us; speedup vs baseline: 1.7124x; 1.1062x over previous
//
#include <hip/hip_runtime.h>
#include <hip/hip_bf16.h>
#include <cstdint>
#include <cstddef>

#define BN_EPS 1e-5f

typedef float f32x4 __attribute__((ext_vector_type(4)));
typedef __bf16 bf16x8 __attribute__((ext_vector_type(8)));

__device__ __forceinline__ unsigned short f2b(float f) {
    unsigned int x = __builtin_bit_cast(unsigned int, f);
    x += 0x7fffu + ((x >> 16) & 1u);          // RNE
    return (unsigned short)(x >> 16);
}
__device__ __forceinline__ float b2f(unsigned short u) {
    return __builtin_bit_cast(float, (unsigned int)u << 16);
}
__device__ __forceinline__ float blo(unsigned int p) {   // low bf16 of packed
    return __builtin_bit_cast(float, p << 16);
}
__device__ __forceinline__ float bhi(unsigned int p) {   // high bf16 of packed
    return __builtin_bit_cast(float, p & 0xffff0000u);
}
__device__ __forceinline__ unsigned int pack2(float lo, float hi) {
    return (unsigned int)f2b(lo) | ((unsigned int)f2b(hi) << 16);
}

// ---------------- init: zero histogram + total counter ----------------
__global__ void init_kernel(int* __restrict__ count, int* __restrict__ gtotal, int n) {
    int i = blockIdx.x * blockDim.x + threadIdx.x;
    if (i < n) count[i] = 0;
    if (i == 0) *gtotal = 0;
}

// ---------------- histogram of dst ----------------
__global__ void count_kernel(const int* __restrict__ ei, int* __restrict__ count, int e) {
    int i = blockIdx.x * blockDim.x + threadIdx.x;
    if (i < e) atomicAdd(&count[ei[e + i]], 1);
}

// ---------------- dinv + row offsets (wave scan + bump allocator) ----------------
__global__ void offsets_kernel(const int* __restrict__ count, float* __restrict__ dinv,
                               int* __restrict__ rowstart, int* __restrict__ cursor,
                               int* __restrict__ gtotal, int n) {
    int i = blockIdx.x * blockDim.x + threadIdx.x;
    int lane = threadIdx.x & 63;
    int v = (i < n) ? count[i] : 0;
    if (i < n) dinv[i] = rsqrtf((float)v + 1.0f);   // deg = indeg + self loop
    int x = v;
    #pragma unroll
    for (int off = 1; off < 64; off <<= 1) {
        int y = __shfl_up(x, off);
        if (lane >= off) x += y;
    }
    int total = __shfl(x, 63);
    int base = 0;
    if (lane == 63) base = atomicAdd(gtotal, total);
    base = __shfl(base, 63);
    int excl = x - v;
    if (i < n) { rowstart[i] = base + excl; cursor[i] = base + excl; }
}

// ---------------- scatter edges into CSR with precomputed weight ----------------
__global__ void scatter_kernel(const int* __restrict__ ei, int* __restrict__ cursor,
                               const float* __restrict__ dinv,
                               int2* __restrict__ edges, int e) {
    int i = blockIdx.x * blockDim.x + threadIdx.x;
    if (i < e) {
        int d = ei[e + i];
        int s = ei[i];
        int pos = atomicAdd(&cursor[d], 1);
        float w = dinv[s] * dinv[d];
        edges[pos] = make_int2(s, __float_as_int(w));
    }
}

// ---------------- f32 -> bf16 convert ----------------
__global__ void cvt_kernel(const float* __restrict__ in, unsigned short* __restrict__ out, int n4) {
    int i = blockIdx.x * blockDim.x + threadIdx.x;
    if (i < n4) {
        float4 v = reinterpret_cast<const float4*>(in)[i];
        uint2 o;
        o.x = pack2(v.x, v.y);
        o.y = pack2(v.z, v.w);
        reinterpret_cast<uint2*>(out)[i] = o;
    }
}

// ---------------- W prep: transpose + bf16 + XOR-swizzle for LDS b128 reads ----------
// out layout: value W[k][c] at ushort index c*128 + ((k>>3)^(c&7))*8 + (k&7)
__global__ void wprep_kernel(const float* __restrict__ W, unsigned short* __restrict__ out, int cols) {
    int i = blockIdx.x * blockDim.x + threadIdx.x;
    if (i >= 128 * cols) return;
    int k = i / cols, c = i % cols;
    int chunk = (k >> 3) ^ (c & 7);
    out[c * 128 + chunk * 8 + (k & 7)] = f2b(W[i]);
}

// ---------------- GCN propagation: TWO nodes per wave (32 lanes each, 8B/lane) -------
// BN=true applies y = relu(v*ca + cb) to each gathered source row (fused BN+ReLU).
template <bool BN>
__global__ __launch_bounds__(256) void prop_kernel(
        const unsigned short* __restrict__ in, unsigned short* __restrict__ out,
        const float* __restrict__ coef,
        const float* __restrict__ dinv, const int* __restrict__ rowstart,
        const int* __restrict__ cnt, const int2* __restrict__ edges, int n) {
    int gw = (blockIdx.x * blockDim.x + threadIdx.x) >> 6;
    int lane = threadIdx.x & 63;
    int half = lane >> 5;
    int hl = lane & 31;
    int node = gw * 2 + half;
    bool act = node < n;
    int nd = act ? node : (n - 1);
    int c0 = hl * 4;

    float4 ca, cb;
    if (BN) {
        ca = *reinterpret_cast<const float4*>(coef + c0);
        cb = *reinterpret_cast<const float4*>(coef + 128 + c0);
    }
    float di = dinv[nd];
    uint2 sp = *reinterpret_cast<const uint2*>(in + (size_t)nd * 128 + c0);
    float v0 = blo(sp.x), v1 = bhi(sp.x), v2 = blo(sp.y), v3 = bhi(sp.y);
    if (BN) {
        v0 = fmaxf(fmaf(v0, ca.x, cb.x), 0.f);
        v1 = fmaxf(fmaf(v1, ca.y, cb.y), 0.f);
        v2 = fmaxf(fmaf(v2, ca.z, cb.z), 0.f);
        v3 = fmaxf(fmaf(v3, ca.w, cb.w), 0.f);
    }
    float ws = di * di;
    float a0 = v0 * ws, a1 = v1 * ws, a2 = v2 * ws, a3 = v3 * ws;

    int beg = rowstart[nd];
    int len = cnt[nd];
    int lmax = max(len, __shfl_xor(len, 32));

    #pragma unroll 2
    for (int t = 0; t < lmax; ++t) {
        bool p = t < len;
        int idx = p ? (beg + t) : beg;      // beg always valid for nd
        int2 e = edges[idx];
        float w = p ? __int_as_float(e.y) : 0.f;
        uint2 u = *reinterpret_cast<const uint2*>(in + (size_t)e.x * 128 + c0);
        float x0 = blo(u.x), x1 = bhi(u.x), x2 = blo(u.y), x3 = bhi(u.y);
        if (BN) {
            x0 = fmaxf(fmaf(x0, ca.x, cb.x), 0.f);
            x1 = fmaxf(fmaf(x1, ca.y, cb.y), 0.f);
            x2 = fmaxf(fmaf(x2, ca.z, cb.z), 0.f);
            x3 = fmaxf(fmaf(x3, ca.w, cb.w), 0.f);
        }
        a0 = fmaf(x0, w, a0);
        a1 = fmaf(x1, w, a1);
        a2 = fmaf(x2, w, a2);
        a3 = fmaf(x3, w, a3);
    }

    if (act) {
        uint2 o;
        o.x = pack2(a0, a1);
        o.y = pack2(a2, a3);
        *reinterpret_cast<uint2*>(out + (size_t)node * 128 + c0) = o;
    }
}

// ---------------- MFMA GEMM: bf16 [n,128] @ [128,COLS] + b, per-block BN partials ----
// 128 rows/block, 4 waves, each wave 32 rows x COLS.
// B pre-transposed+swizzled in global (wprep), staged linearly into LDS.
// STATS: per-thread partials -> shfl reduce -> LDS -> one coalesced row in statsP.
template <int COLS, bool OUT_BF, bool STATS>
__global__ __launch_bounds__(256) void gemm_kernel(
        const unsigned short* __restrict__ A, const unsigned short* __restrict__ Bswz,
        const float* __restrict__ bias, void* __restrict__ out,
        float* __restrict__ statsP, int n) {
    constexpr int NT = COLS / 16;
    __shared__ unsigned short Blds[128 * COLS];
    __shared__ float s_sum[128];
    __shared__ float s_sq[128];

    int t = threadIdx.x;
    int w = t >> 6, l = t & 63;
    int lr = l & 15, lg = l >> 4;
    int row_base = blockIdx.x * 128 + w * 32;

    // A fragments first (longest-latency gathers in flight early)
    bf16x8 a[2][4];
    #pragma unroll
    for (int m = 0; m < 2; ++m) {
        int row = min(row_base + m * 16 + lr, n - 1);
        const unsigned short* ap = A + (size_t)row * 128 + lg * 8;
        #pragma unroll
        for (int kb = 0; kb < 4; ++kb)
            a[m][kb] = *reinterpret_cast<const bf16x8*>(ap + kb * 32);
    }

    // stage swizzled B linearly (conflict-free)
    constexpr int WORDS16 = 128 * COLS * 2 / 16;   // uint4 chunks
    for (int i = t; i < WORDS16; i += 256)
        reinterpret_cast<uint4*>(Blds)[i] = reinterpret_cast<const uint4*>(Bswz)[i];
    if (STATS) {
        if (t < 128) { s_sum[t] = 0.f; s_sq[t] = 0.f; }
    }

    f32x4 acc[2][NT];
    #pragma unroll
    for (int m = 0; m < 2; ++m)
        #pragma unroll
        for (int nn = 0; nn < NT; ++nn)
            acc[m][nn] = f32x4{0.f, 0.f, 0.f, 0.f};

    __syncthreads();

    #pragma unroll
    for (int kb = 0; kb < 4; ++kb) {
        bf16x8 b[NT];
        #pragma unroll
        for (int nn = 0; nn < NT; ++nn) {
            int c = nn * 16 + lr;
            int chunk = (kb * 4 + lg) ^ (c & 7);
            b[nn] = *reinterpret_cast<const bf16x8*>(
                        reinterpret_cast<const char*>(Blds) + c * 256 + chunk * 16);
        }
        #pragma unroll
        for (int m = 0; m < 2; ++m)
            #pragma unroll
            for (int nn = 0; nn < NT; ++nn)
                acc[m][nn] = __builtin_amdgcn_mfma_f32_16x16x32_bf16(a[m][kb], b[nn], acc[m][nn], 0, 0, 0);
    }

    // epilogue: D layout col = lr, row = lg*4 + q
    float ps[NT], pq[NT];
    #pragma unroll
    for (int nn = 0; nn < NT; ++nn) { ps[nn] = 0.f; pq[nn] = 0.f; }
    #pragma unroll
    for (int m = 0; m < 2; ++m) {
        #pragma unroll
        for (int nn = 0; nn < NT; ++nn) {
            int col = nn * 16 + lr;
            float bb = bias[col];
            #pragma unroll
            for (int q = 0; q < 4; ++q) {
                int row = row_base + m * 16 + lg * 4 + q;
                float v = acc[m][nn][q] + bb;
                if (row < n) {
                    if (OUT_BF)
                        reinterpret_cast<unsigned short*>(out)[(size_t)row * COLS + col] = f2b(v);
                    else
                        reinterpret_cast<float*>(out)[(size_t)row * COLS + col] = v;
                    if (STATS) { ps[nn] += v; pq[nn] += v * v; }
                }
            }
        }
    }

    if (STATS) {
        // reduce across lg (lanes xor 16, 32) -> lanes 0..15 hold column totals
        #pragma unroll
        for (int nn = 0; nn < NT; ++nn) {
            float s = ps[nn], q = pq[nn];
            s += __shfl_xor(s, 16); s += __shfl_xor(s, 32);
            q += __shfl_xor(q, 16); q += __shfl_xor(q, 32);
            if (lg == 0) {
                atomicAdd(&s_sum[nn * 16 + lr], s);   // 4 waves combine
                atomicAdd(&s_sq[nn * 16 + lr], q);
            }
        }
        __syncthreads();
        float* row = statsP + (size_t)blockIdx.x * 256;
        if (t < 128) row[t] = s_sum[t];
        else         row[t] = s_sq[t - 128];
    }
}

// ---------------- column-wise reduce of per-block stats partials ----------------
__global__ void reduce_kernel(const float* __restrict__ sp, float* __restrict__ stats, int nb) {
    int c = blockIdx.x;          // 0..255
    float s = 0.f;
    for (int b = threadIdx.x; b < nb; b += 256)
        s += sp[(size_t)b * 256 + c];
    #pragma unroll
    for (int off = 32; off > 0; off >>= 1) s += __shfl_down(s, off);
    __shared__ float w4[4];
    if ((threadIdx.x & 63) == 0) w4[threadIdx.x >> 6] = s;
    __syncthreads();
    if (threadIdx.x == 0) stats[c] = w4[0] + w4[1] + w4[2] + w4[3];
}

// ---------------- BN coefficients ----------------
__global__ void coef_kernel(const float* __restrict__ stats, const float* __restrict__ g,
                            const float* __restrict__ be, float* __restrict__ coef, int n) {
    int j = threadIdx.x;
    if (j < 128) {
        float inv_n = 1.0f / (float)n;
        float mean = stats[j] * inv_n;
        float var = stats[128 + j] * inv_n - mean * mean;
        float a = g[j] * rsqrtf(var + BN_EPS);
        coef[j] = a;
        coef[128 + j] = be[j] - mean * a;
    }
}

// ---------------- decode: sigmoid(dot(emb[a], emb[b])) over bf16 emb ----------------
// lanes 0..31 carry row a, lanes 32..63 carry row b; one 8B load per lane.
__global__ void decode_kernel(const unsigned short* __restrict__ emb, const int* __restrict__ lab,
                              float* __restrict__ r, int elab) {
    int wid = (blockIdx.x * blockDim.x + threadIdx.x) >> 6;
    int lane = threadIdx.x & 63;
    if (wid >= elab) return;
    int a = lab[wid], b = lab[elab + wid];
    int row = (lane < 32) ? a : b;
    int c0 = (lane & 31) * 4;
    uint2 u = *reinterpret_cast<const uint2*>(emb + (size_t)row * 128 + c0);
    uint2 o;
    o.x = __shfl_xor(u.x, 32);
    o.y = __shfl_xor(u.y, 32);
    float s = blo(u.x) * blo(o.x) + bhi(u.x) * bhi(o.x)
            + blo(u.y) * blo(o.y) + bhi(u.y) * bhi(o.y);
    #pragma unroll
    for (int off = 16; off > 0; off >>= 1) s += __shfl_xor(s, off);
    if (lane == 0) r[wid] = 1.0f / (1.0f + expf(-s));
}

static inline char* carve(char*& p, size_t bytes) {
    char* r = p;
    p += (bytes + 255) & ~(size_t)255;
    return r;
}

extern "C" void kernel_launch(void* const* d_in, const int* in_sizes, int n_in,
                              void* d_out, int out_size, void* d_ws, size_t ws_size,
                              hipStream_t stream) {
    const float* x   = (const float*)d_in[0];
    const int*   ei  = (const int*)d_in[1];
    const int*   lab = (const int*)d_in[2];
    const float* W1 = (const float*)d_in[3],  *b1 = (const float*)d_in[4];
    const float* g1 = (const float*)d_in[5],  *be1 = (const float*)d_in[6];
    const float* W2 = (const float*)d_in[7],  *b2 = (const float*)d_in[8];
    const float* g2 = (const float*)d_in[9],  *be2 = (const float*)d_in[10];
    const float* W3 = (const float*)d_in[11], *b3 = (const float*)d_in[12];

    const int N = in_sizes[0] / 128;
    const int E = in_sizes[1] / 2;
    const int ELAB = in_sizes[2] / 2;

    int gG = (N + 127) / 128;

    char* p = (char*)d_ws;
    int*   count    = (int*)carve(p, (size_t)N * 4);
    int*   cursor   = (int*)carve(p, (size_t)N * 4);
    int*   rowstart = (int*)carve(p, (size_t)N * 4);
    float* dinv     = (float*)carve(p, (size_t)N * 4);
    int2*  edges    = (int2*)carve(p, (size_t)E * 8);
    int*   gtotal   = (int*)carve(p, 256);
    float* statsP   = (float*)carve(p, (size_t)gG * 256 * 4);
    float* stats1   = (float*)carve(p, 256 * 4);
    float* stats2   = (float*)carve(p, 256 * 4);
    float* coef1    = (float*)carve(p, 256 * 4);
    float* coef2    = (float*)carve(p, 256 * 4);
    unsigned short* Wt1 = (unsigned short*)carve(p, 128 * 128 * 2);
    unsigned short* Wt2 = (unsigned short*)carve(p, 128 * 128 * 2);
    unsigned short* Wt3 = (unsigned short*)carve(p, 128 * 64 * 2);
    unsigned short* xb  = (unsigned short*)carve(p, (size_t)N * 128 * 2);
    unsigned short* bA  = (unsigned short*)carve(p, (size_t)N * 128 * 2);
    unsigned short* bB  = (unsigned short*)carve(p, (size_t)N * 128 * 2);

    dim3 blk(256);
    int gN   = (N + 255) / 256;
    int gE   = (E + 255) / 256;
    int nWP  = (N + 1) / 2;                 // prop waves (2 nodes each)
    int gWN  = (nWP * 64 + 255) / 256;
    int gWL  = (ELAB * 64 + 255) / 256;
    int g4   = (N * 32 + 255) / 256;

    // build CSR + preps
    init_kernel<<<gN, blk, 0, stream>>>(count, gtotal, N);
    count_kernel<<<gE, blk, 0, stream>>>(ei, count, E);
    offsets_kernel<<<gN, blk, 0, stream>>>(count, dinv, rowstart, cursor, gtotal, N);
    scatter_kernel<<<gE, blk, 0, stream>>>(ei, cursor, dinv, edges, E);
    cvt_kernel<<<g4, blk, 0, stream>>>(x, xb, N * 32);
    wprep_kernel<<<64, blk, 0, stream>>>(W1, Wt1, 128);
    wprep_kernel<<<64, blk, 0, stream>>>(W2, Wt2, 128);
    wprep_kernel<<<32, blk, 0, stream>>>(W3, Wt3, 64);

    // layer 1
    prop_kernel<false><<<gWN, blk, 0, stream>>>(xb, bA, nullptr, dinv, rowstart, count, edges, N);
    gemm_kernel<128, true, true><<<gG, blk, 0, stream>>>(bA, Wt1, b1, bB, statsP, N);
    reduce_kernel<<<256, blk, 0, stream>>>(statsP, stats1, gG);
    coef_kernel<<<1, 128, 0, stream>>>(stats1, g1, be1, coef1, N);

    // layer 2 (BN+ReLU of layer 1 fused into prop's read path)
    prop_kernel<true><<<gWN, blk, 0, stream>>>(bB, bA, coef1, dinv, rowstart, count, edges, N);
    gemm_kernel<128, true, true><<<gG, blk, 0, stream>>>(bA, Wt2, b2, bB, statsP, N);
    reduce_kernel<<<256, blk, 0, stream>>>(statsP, stats2, gG);
    coef_kernel<<<1, 128, 0, stream>>>(stats2, g2, be2, coef2, N);

    // layer 3: emb = prop(relu(bn(h2))); x_out = emb @ W3 + b3; r = sigmoid(<emb,emb>)
    prop_kernel<true><<<gWN, blk, 0, stream>>>(bB, bA, coef2, dinv, rowstart, count, edges, N);
    gemm_kernel<64, false, false><<<gG, blk, 0, stream>>>(bA, Wt3, b3, (float*)d_out, nullptr, N);
    decode_kernel<<<gWL, blk, 0, stream>>>(bA, lab, (float*)d_out + (size_t)N * 64, ELAB);
}

// Round 5
// 396.758 us; speedup vs baseline: 1.8551x; 1.0833x over previous
//
#include <hip/hip_runtime.h>
#include <hip/hip_bf16.h>
#include <cstdint>
#include <cstddef>

#define BN_EPS 1e-5f

typedef float f32x4 __attribute__((ext_vector_type(4)));
typedef __bf16 bf16x8 __attribute__((ext_vector_type(8)));

__device__ __forceinline__ unsigned short f2b(float f) {
    unsigned int x = __builtin_bit_cast(unsigned int, f);
    x += 0x7fffu + ((x >> 16) & 1u);          // RNE
    return (unsigned short)(x >> 16);
}
__device__ __forceinline__ float b2f(unsigned short u) {
    return __builtin_bit_cast(float, (unsigned int)u << 16);
}
__device__ __forceinline__ float blo(unsigned int p) {   // low bf16 of packed
    return __builtin_bit_cast(float, p << 16);
}
__device__ __forceinline__ float bhi(unsigned int p) {   // high bf16 of packed
    return __builtin_bit_cast(float, p & 0xffff0000u);
}
__device__ __forceinline__ unsigned int pack2(float lo, float hi) {
    return (unsigned int)f2b(lo) | ((unsigned int)f2b(hi) << 16);
}

// ---------------- init: zero histogram + total counter ----------------
__global__ void init_kernel(int* __restrict__ count, int* __restrict__ gtotal, int n) {
    int i = blockIdx.x * blockDim.x + threadIdx.x;
    if (i < n) count[i] = 0;
    if (i == 0) *gtotal = 0;
}

// ---------------- histogram of dst ----------------
__global__ void count_kernel(const int* __restrict__ ei, int* __restrict__ count, int e) {
    int i = blockIdx.x * blockDim.x + threadIdx.x;
    if (i < e) atomicAdd(&count[ei[e + i]], 1);
}

// ---------------- dinv + row offsets (wave scan + bump allocator) ----------------
__global__ void offsets_kernel(const int* __restrict__ count, float* __restrict__ dinv,
                               int* __restrict__ rowstart, int* __restrict__ cursor,
                               int* __restrict__ gtotal, int n) {
    int i = blockIdx.x * blockDim.x + threadIdx.x;
    int lane = threadIdx.x & 63;
    int v = (i < n) ? count[i] : 0;
    if (i < n) dinv[i] = rsqrtf((float)v + 1.0f);   // deg = indeg + self loop
    int x = v;
    #pragma unroll
    for (int off = 1; off < 64; off <<= 1) {
        int y = __shfl_up(x, off);
        if (lane >= off) x += y;
    }
    int total = __shfl(x, 63);
    int base = 0;
    if (lane == 63) base = atomicAdd(gtotal, total);
    base = __shfl(base, 63);
    int excl = x - v;
    if (i < n) { rowstart[i] = base + excl; cursor[i] = base + excl; }
}

// ---------------- scatter edges into CSR with precomputed weight ----------------
__global__ void scatter_kernel(const int* __restrict__ ei, int* __restrict__ cursor,
                               const float* __restrict__ dinv,
                               int2* __restrict__ edges, int e) {
    int i = blockIdx.x * blockDim.x + threadIdx.x;
    if (i < e) {
        int d = ei[e + i];
        int s = ei[i];
        int pos = atomicAdd(&cursor[d], 1);
        float w = dinv[s] * dinv[d];
        edges[pos] = make_int2(s, __float_as_int(w));
    }
}

// ---------------- f32 -> bf16 convert ----------------
__global__ void cvt_kernel(const float* __restrict__ in, unsigned short* __restrict__ out, int n4) {
    int i = blockIdx.x * blockDim.x + threadIdx.x;
    if (i < n4) {
        float4 v = reinterpret_cast<const float4*>(in)[i];
        uint2 o;
        o.x = pack2(v.x, v.y);
        o.y = pack2(v.z, v.w);
        reinterpret_cast<uint2*>(out)[i] = o;
    }
}

// ---------------- W prep (all 3): transpose + bf16 + XOR-swizzle -------------------
// out layout: value W[k][c] at ushort index c*128 + ((k>>3)^(c&7))*8 + (k&7)
__device__ __forceinline__ void wprep_one(const float* __restrict__ W,
                                          unsigned short* __restrict__ out, int cols, int i) {
    int k = i / cols, c = i % cols;
    int chunk = (k >> 3) ^ (c & 7);
    out[c * 128 + chunk * 8 + (k & 7)] = f2b(W[i]);
}
__global__ void wprep_all_kernel(const float* __restrict__ W1, unsigned short* __restrict__ o1,
                                 const float* __restrict__ W2, unsigned short* __restrict__ o2,
                                 const float* __restrict__ W3, unsigned short* __restrict__ o3) {
    int i = blockIdx.x * blockDim.x + threadIdx.x;
    if (i < 16384)       wprep_one(W1, o1, 128, i);
    else if (i < 32768)  wprep_one(W2, o2, 128, i - 16384);
    else if (i < 40960)  wprep_one(W3, o3, 64, i - 32768);
}

// ---------------- GCN propagation: TWO nodes per wave, 4-edge software pipeline -----
// BN=true applies y = relu(v*ca + cb) to each gathered source row (fused BN+ReLU).
template <bool BN>
__global__ __launch_bounds__(256) void prop_kernel(
        const unsigned short* __restrict__ in, unsigned short* __restrict__ out,
        const float* __restrict__ coef,
        const float* __restrict__ dinv, const int* __restrict__ rowstart,
        const int* __restrict__ cnt, const int2* __restrict__ edges, int n) {
    int gw = (blockIdx.x * blockDim.x + threadIdx.x) >> 6;
    int lane = threadIdx.x & 63;
    int half = lane >> 5;
    int hl = lane & 31;
    int node = gw * 2 + half;
    bool act = node < n;
    int nd = act ? node : (n - 1);
    int c0 = hl * 4;

    float4 ca, cb;
    if (BN) {
        ca = *reinterpret_cast<const float4*>(coef + c0);
        cb = *reinterpret_cast<const float4*>(coef + 128 + c0);
    }
    float di = dinv[nd];
    uint2 sp = *reinterpret_cast<const uint2*>(in + (size_t)nd * 128 + c0);
    float v0 = blo(sp.x), v1 = bhi(sp.x), v2 = blo(sp.y), v3 = bhi(sp.y);
    if (BN) {
        v0 = fmaxf(fmaf(v0, ca.x, cb.x), 0.f);
        v1 = fmaxf(fmaf(v1, ca.y, cb.y), 0.f);
        v2 = fmaxf(fmaf(v2, ca.z, cb.z), 0.f);
        v3 = fmaxf(fmaf(v3, ca.w, cb.w), 0.f);
    }
    float ws = di * di;
    float a0 = v0 * ws, a1 = v1 * ws, a2 = v2 * ws, a3 = v3 * ws;

    int beg = rowstart[nd];
    int len = cnt[nd];
    int lmax = max(len, __shfl_xor(len, 32));
    int last = beg + ((len > 0) ? (len - 1) : 0);   // clamp target (always valid memory)

    for (int t = 0; t < lmax; t += 4) {
        // 4 independent edge records (broadcast within half-wave)
        int2 e0 = edges[min(beg + t + 0, last)];
        int2 e1 = edges[min(beg + t + 1, last)];
        int2 e2 = edges[min(beg + t + 2, last)];
        int2 e3 = edges[min(beg + t + 3, last)];
        // 4 independent row gathers in flight
        uint2 u0 = *reinterpret_cast<const uint2*>(in + (size_t)e0.x * 128 + c0);
        uint2 u1 = *reinterpret_cast<const uint2*>(in + (size_t)e1.x * 128 + c0);
        uint2 u2 = *reinterpret_cast<const uint2*>(in + (size_t)e2.x * 128 + c0);
        uint2 u3 = *reinterpret_cast<const uint2*>(in + (size_t)e3.x * 128 + c0);
        float w0 = (t + 0 < len) ? __int_as_float(e0.y) : 0.f;
        float w1 = (t + 1 < len) ? __int_as_float(e1.y) : 0.f;
        float w2 = (t + 2 < len) ? __int_as_float(e2.y) : 0.f;
        float w3 = (t + 3 < len) ? __int_as_float(e3.y) : 0.f;

        float x0, x1, x2, x3;
        x0 = blo(u0.x); x1 = bhi(u0.x); x2 = blo(u0.y); x3 = bhi(u0.y);
        if (BN) {
            x0 = fmaxf(fmaf(x0, ca.x, cb.x), 0.f); x1 = fmaxf(fmaf(x1, ca.y, cb.y), 0.f);
            x2 = fmaxf(fmaf(x2, ca.z, cb.z), 0.f); x3 = fmaxf(fmaf(x3, ca.w, cb.w), 0.f);
        }
        a0 = fmaf(x0, w0, a0); a1 = fmaf(x1, w0, a1); a2 = fmaf(x2, w0, a2); a3 = fmaf(x3, w0, a3);

        x0 = blo(u1.x); x1 = bhi(u1.x); x2 = blo(u1.y); x3 = bhi(u1.y);
        if (BN) {
            x0 = fmaxf(fmaf(x0, ca.x, cb.x), 0.f); x1 = fmaxf(fmaf(x1, ca.y, cb.y), 0.f);
            x2 = fmaxf(fmaf(x2, ca.z, cb.z), 0.f); x3 = fmaxf(fmaf(x3, ca.w, cb.w), 0.f);
        }
        a0 = fmaf(x0, w1, a0); a1 = fmaf(x1, w1, a1); a2 = fmaf(x2, w1, a2); a3 = fmaf(x3, w1, a3);

        x0 = blo(u2.x); x1 = bhi(u2.x); x2 = blo(u2.y); x3 = bhi(u2.y);
        if (BN) {
            x0 = fmaxf(fmaf(x0, ca.x, cb.x), 0.f); x1 = fmaxf(fmaf(x1, ca.y, cb.y), 0.f);
            x2 = fmaxf(fmaf(x2, ca.z, cb.z), 0.f); x3 = fmaxf(fmaf(x3, ca.w, cb.w), 0.f);
        }
        a0 = fmaf(x0, w2, a0); a1 = fmaf(x1, w2, a1); a2 = fmaf(x2, w2, a2); a3 = fmaf(x3, w2, a3);

        x0 = blo(u3.x); x1 = bhi(u3.x); x2 = blo(u3.y); x3 = bhi(u3.y);
        if (BN) {
            x0 = fmaxf(fmaf(x0, ca.x, cb.x), 0.f); x1 = fmaxf(fmaf(x1, ca.y, cb.y), 0.f);
            x2 = fmaxf(fmaf(x2, ca.z, cb.z), 0.f); x3 = fmaxf(fmaf(x3, ca.w, cb.w), 0.f);
        }
        a0 = fmaf(x0, w3, a0); a1 = fmaf(x1, w3, a1); a2 = fmaf(x2, w3, a2); a3 = fmaf(x3, w3, a3);
    }

    if (act) {
        uint2 o;
        o.x = pack2(a0, a1);
        o.y = pack2(a2, a3);
        *reinterpret_cast<uint2*>(out + (size_t)node * 128 + c0) = o;
    }
}

// ---------------- MFMA GEMM: bf16 [n,128] @ [128,COLS] + b, per-block BN partials ----
template <int COLS, bool OUT_BF, bool STATS>
__global__ __launch_bounds__(256) void gemm_kernel(
        const unsigned short* __restrict__ A, const unsigned short* __restrict__ Bswz,
        const float* __restrict__ bias, void* __restrict__ out,
        float* __restrict__ statsP, int n) {
    constexpr int NT = COLS / 16;
    __shared__ unsigned short Blds[128 * COLS];
    __shared__ float s_sum[128];
    __shared__ float s_sq[128];

    int t = threadIdx.x;
    int w = t >> 6, l = t & 63;
    int lr = l & 15, lg = l >> 4;
    int row_base = blockIdx.x * 128 + w * 32;

    // A fragments first (longest-latency gathers in flight early)
    bf16x8 a[2][4];
    #pragma unroll
    for (int m = 0; m < 2; ++m) {
        int row = min(row_base + m * 16 + lr, n - 1);
        const unsigned short* ap = A + (size_t)row * 128 + lg * 8;
        #pragma unroll
        for (int kb = 0; kb < 4; ++kb)
            a[m][kb] = *reinterpret_cast<const bf16x8*>(ap + kb * 32);
    }

    // stage swizzled B linearly (conflict-free)
    constexpr int WORDS16 = 128 * COLS * 2 / 16;   // uint4 chunks
    for (int i = t; i < WORDS16; i += 256)
        reinterpret_cast<uint4*>(Blds)[i] = reinterpret_cast<const uint4*>(Bswz)[i];
    if (STATS) {
        if (t < 128) { s_sum[t] = 0.f; s_sq[t] = 0.f; }
    }

    f32x4 acc[2][NT];
    #pragma unroll
    for (int m = 0; m < 2; ++m)
        #pragma unroll
        for (int nn = 0; nn < NT; ++nn)
            acc[m][nn] = f32x4{0.f, 0.f, 0.f, 0.f};

    __syncthreads();

    #pragma unroll
    for (int kb = 0; kb < 4; ++kb) {
        bf16x8 b[NT];
        #pragma unroll
        for (int nn = 0; nn < NT; ++nn) {
            int c = nn * 16 + lr;
            int chunk = (kb * 4 + lg) ^ (c & 7);
            b[nn] = *reinterpret_cast<const bf16x8*>(
                        reinterpret_cast<const char*>(Blds) + c * 256 + chunk * 16);
        }
        #pragma unroll
        for (int m = 0; m < 2; ++m)
            #pragma unroll
            for (int nn = 0; nn < NT; ++nn)
                acc[m][nn] = __builtin_amdgcn_mfma_f32_16x16x32_bf16(a[m][kb], b[nn], acc[m][nn], 0, 0, 0);
    }

    // epilogue: D layout col = lr, row = lg*4 + q
    float ps[NT], pq[NT];
    #pragma unroll
    for (int nn = 0; nn < NT; ++nn) { ps[nn] = 0.f; pq[nn] = 0.f; }
    #pragma unroll
    for (int m = 0; m < 2; ++m) {
        #pragma unroll
        for (int nn = 0; nn < NT; ++nn) {
            int col = nn * 16 + lr;
            float bb = bias[col];
            #pragma unroll
            for (int q = 0; q < 4; ++q) {
                int row = row_base + m * 16 + lg * 4 + q;
                float v = acc[m][nn][q] + bb;
                if (row < n) {
                    if (OUT_BF)
                        reinterpret_cast<unsigned short*>(out)[(size_t)row * COLS + col] = f2b(v);
                    else
                        reinterpret_cast<float*>(out)[(size_t)row * COLS + col] = v;
                    if (STATS) { ps[nn] += v; pq[nn] += v * v; }
                }
            }
        }
    }

    if (STATS) {
        #pragma unroll
        for (int nn = 0; nn < NT; ++nn) {
            float s = ps[nn], q = pq[nn];
            s += __shfl_xor(s, 16); s += __shfl_xor(s, 32);
            q += __shfl_xor(q, 16); q += __shfl_xor(q, 32);
            if (lg == 0) {
                atomicAdd(&s_sum[nn * 16 + lr], s);   // 4 waves combine
                atomicAdd(&s_sq[nn * 16 + lr], q);
            }
        }
        __syncthreads();
        float* row = statsP + (size_t)blockIdx.x * 256;
        if (t < 128) row[t] = s_sum[t];
        else         row[t] = s_sq[t - 128];
    }
}

// ---------------- column reduce of per-block partials + BN coefficients -------------
__global__ void reduce_coef_kernel(const float* __restrict__ sp,
                                   const float* __restrict__ g, const float* __restrict__ be,
                                   float* __restrict__ coef, int nb, int n) {
    int c = blockIdx.x;          // 0..127
    float s = 0.f, q = 0.f;
    for (int b = threadIdx.x; b < nb; b += 256) {
        const float* row = sp + (size_t)b * 256;
        s += row[c];
        q += row[128 + c];
    }
    #pragma unroll
    for (int off = 32; off > 0; off >>= 1) {
        s += __shfl_xor(s, off);
        q += __shfl_xor(q, off);
    }
    __shared__ float ws4[4], wq4[4];
    int w = threadIdx.x >> 6;
    if ((threadIdx.x & 63) == 0) { ws4[w] = s; wq4[w] = q; }
    __syncthreads();
    if (threadIdx.x == 0) {
        float S = ws4[0] + ws4[1] + ws4[2] + ws4[3];
        float Q = wq4[0] + wq4[1] + wq4[2] + wq4[3];
        float inv_n = 1.0f / (float)n;
        float mean = S * inv_n;
        float var = Q * inv_n - mean * mean;
        float a = g[c] * rsqrtf(var + BN_EPS);
        coef[c] = a;
        coef[128 + c] = be[c] - mean * a;
    }
}

// ---------------- decode: sigmoid(dot(emb[a], emb[b])) over bf16 emb ----------------
__global__ void decode_kernel(const unsigned short* __restrict__ emb, const int* __restrict__ lab,
                              float* __restrict__ r, int elab) {
    int wid = (blockIdx.x * blockDim.x + threadIdx.x) >> 6;
    int lane = threadIdx.x & 63;
    if (wid >= elab) return;
    int a = lab[wid], b = lab[elab + wid];
    int row = (lane < 32) ? a : b;
    int c0 = (lane & 31) * 4;
    uint2 u = *reinterpret_cast<const uint2*>(emb + (size_t)row * 128 + c0);
    uint2 o;
    o.x = __shfl_xor(u.x, 32);
    o.y = __shfl_xor(u.y, 32);
    float s = blo(u.x) * blo(o.x) + bhi(u.x) * bhi(o.x)
            + blo(u.y) * blo(o.y) + bhi(u.y) * bhi(o.y);
    #pragma unroll
    for (int off = 16; off > 0; off >>= 1) s += __shfl_xor(s, off);
    if (lane == 0) r[wid] = 1.0f / (1.0f + expf(-s));
}

static inline char* carve(char*& p, size_t bytes) {
    char* r = p;
    p += (bytes + 255) & ~(size_t)255;
    return r;
}

extern "C" void kernel_launch(void* const* d_in, const int* in_sizes, int n_in,
                              void* d_out, int out_size, void* d_ws, size_t ws_size,
                              hipStream_t stream) {
    const float* x   = (const float*)d_in[0];
    const int*   ei  = (const int*)d_in[1];
    const int*   lab = (const int*)d_in[2];
    const float* W1 = (const float*)d_in[3],  *b1 = (const float*)d_in[4];
    const float* g1 = (const float*)d_in[5],  *be1 = (const float*)d_in[6];
    const float* W2 = (const float*)d_in[7],  *b2 = (const float*)d_in[8];
    const float* g2 = (const float*)d_in[9],  *be2 = (const float*)d_in[10];
    const float* W3 = (const float*)d_in[11], *b3 = (const float*)d_in[12];

    const int N = in_sizes[0] / 128;
    const int E = in_sizes[1] / 2;
    const int ELAB = in_sizes[2] / 2;

    int gG = (N + 127) / 128;

    char* p = (char*)d_ws;
    int*   count    = (int*)carve(p, (size_t)N * 4);
    int*   cursor   = (int*)carve(p, (size_t)N * 4);
    int*   rowstart = (int*)carve(p, (size_t)N * 4);
    float* dinv     = (float*)carve(p, (size_t)N * 4);
    int2*  edges    = (int2*)carve(p, (size_t)E * 8);
    int*   gtotal   = (int*)carve(p, 256);
    float* statsP   = (float*)carve(p, (size_t)gG * 256 * 4);
    float* coef1    = (float*)carve(p, 256 * 4);
    float* coef2    = (float*)carve(p, 256 * 4);
    unsigned short* Wt1 = (unsigned short*)carve(p, 128 * 128 * 2);
    unsigned short* Wt2 = (unsigned short*)carve(p, 128 * 128 * 2);
    unsigned short* Wt3 = (unsigned short*)carve(p, 128 * 64 * 2);
    unsigned short* xb  = (unsigned short*)carve(p, (size_t)N * 128 * 2);
    unsigned short* bA  = (unsigned short*)carve(p, (size_t)N * 128 * 2);
    unsigned short* bB  = (unsigned short*)carve(p, (size_t)N * 128 * 2);

    dim3 blk(256);
    int gN   = (N + 255) / 256;
    int gE   = (E + 255) / 256;
    int nWP  = (N + 1) / 2;                 // prop waves (2 nodes each)
    int gWN  = (nWP * 64 + 255) / 256;
    int gWL  = (ELAB * 64 + 255) / 256;
    int g4   = (N * 32 + 255) / 256;

    // build CSR + preps
    init_kernel<<<gN, blk, 0, stream>>>(count, gtotal, N);
    count_kernel<<<gE, blk, 0, stream>>>(ei, count, E);
    offsets_kernel<<<gN, blk, 0, stream>>>(count, dinv, rowstart, cursor, gtotal, N);
    scatter_kernel<<<gE, blk, 0, stream>>>(ei, cursor, dinv, edges, E);
    cvt_kernel<<<g4, blk, 0, stream>>>(x, xb, N * 32);
    wprep_all_kernel<<<160, blk, 0, stream>>>(W1, Wt1, W2, Wt2, W3, Wt3);

    // layer 1
    prop_kernel<false><<<gWN, blk, 0, stream>>>(xb, bA, nullptr, dinv, rowstart, count, edges, N);
    gemm_kernel<128, true, true><<<gG, blk, 0, stream>>>(bA, Wt1, b1, bB, statsP, N);
    reduce_coef_kernel<<<128, blk, 0, stream>>>(statsP, g1, be1, coef1, gG, N);

    // layer 2 (BN+ReLU of layer 1 fused into prop's read path)
    prop_kernel<true><<<gWN, blk, 0, stream>>>(bB, bA, coef1, dinv, rowstart, count, edges, N);
    gemm_kernel<128, true, true><<<gG, blk, 0, stream>>>(bA, Wt2, b2, bB, statsP, N);
    reduce_coef_kernel<<<128, blk, 0, stream>>>(statsP, g2, be2, coef2, gG, N);

    // layer 3: emb = prop(relu(bn(h2))); x_out = emb @ W3 + b3; r = sigmoid(<emb,emb>)
    prop_kernel<true><<<gWN, blk, 0, stream>>>(bB, bA, coef2, dinv, rowstart, count, edges, N);
    gemm_kernel<64, false, false><<<gG, blk, 0, stream>>>(bA, Wt3, b3, (float*)d_out, nullptr, N);
    decode_kernel<<<gWL, blk, 0, stream>>>(bA, lab, (float*)d_out + (size_t)N * 64, ELAB);
}

// Round 7
// 379.684 us; speedup vs baseline: 1.9386x; 1.0450x over previous
//
#include <hip/hip_runtime.h>
#include <hip/hip_bf16.h>
#include <cstdint>
#include <cstddef>

#define BN_EPS 1e-5f

typedef float f32x4 __attribute__((ext_vector_type(4)));
typedef __bf16 bf16x8 __attribute__((ext_vector_type(8)));

__device__ __forceinline__ unsigned short f2b(float f) {
    unsigned int x = __builtin_bit_cast(unsigned int, f);
    x += 0x7fffu + ((x >> 16) & 1u);          // RNE
    return (unsigned short)(x >> 16);
}
__device__ __forceinline__ float blo(unsigned int p) {   // low bf16 of packed
    return __builtin_bit_cast(float, p << 16);
}
__device__ __forceinline__ float bhi(unsigned int p) {   // high bf16 of packed
    return __builtin_bit_cast(float, p & 0xffff0000u);
}
__device__ __forceinline__ unsigned int pack2(float lo, float hi) {
    return (unsigned int)f2b(lo) | ((unsigned int)f2b(hi) << 16);
}

// ---------------- W prep helper: transpose + bf16 + XOR-swizzle ---------------------
// out layout: value W[k][c] at ushort index c*128 + ((k>>3)^(c&7))*8 + (k&7)
__device__ __forceinline__ void wprep_one(const float* __restrict__ W,
                                          unsigned short* __restrict__ out, int cols, int i) {
    int k = i / cols, c = i % cols;
    int chunk = (k >> 3) ^ (c & 7);
    out[c * 128 + chunk * 8 + (k & 7)] = f2b(W[i]);
}

// ---------------- fused prep: cvt x->bf16, zero count/gtotal, wprep all 3 -----------
__global__ void prep_kernel(const float* __restrict__ x, unsigned short* __restrict__ xb, int n4,
                            int* __restrict__ count, int* __restrict__ gtotal, int n,
                            const float* __restrict__ W1, unsigned short* __restrict__ o1,
                            const float* __restrict__ W2, unsigned short* __restrict__ o2,
                            const float* __restrict__ W3, unsigned short* __restrict__ o3) {
    int i = blockIdx.x * blockDim.x + threadIdx.x;
    if (i < n4) {
        float4 v = reinterpret_cast<const float4*>(x)[i];
        uint2 o;
        o.x = pack2(v.x, v.y);
        o.y = pack2(v.z, v.w);
        reinterpret_cast<uint2*>(xb)[i] = o;
    }
    if (i < n) count[i] = 0;
    if (i == 0) *gtotal = 0;
    if (i < 16384)       wprep_one(W1, o1, 128, i);
    else if (i < 32768)  wprep_one(W2, o2, 128, i - 16384);
    else if (i < 40960)  wprep_one(W3, o3, 64, i - 32768);
}

// ---------------- histogram of dst ----------------
__global__ void count_kernel(const int* __restrict__ ei, int* __restrict__ count, int e) {
    int i = blockIdx.x * blockDim.x + threadIdx.x;
    if (i < e) atomicAdd(&count[ei[e + i]], 1);
}

// ---------------- dinv + row offsets (wave scan + bump allocator) ----------------
__global__ void offsets_kernel(const int* __restrict__ count, float* __restrict__ dinv,
                               int* __restrict__ rowstart, int* __restrict__ cursor,
                               int* __restrict__ gtotal, int n) {
    int i = blockIdx.x * blockDim.x + threadIdx.x;
    int lane = threadIdx.x & 63;
    int v = (i < n) ? count[i] : 0;
    if (i < n) dinv[i] = rsqrtf((float)v + 1.0f);   // deg = indeg + self loop
    int x = v;
    #pragma unroll
    for (int off = 1; off < 64; off <<= 1) {
        int y = __shfl_up(x, off);
        if (lane >= off) x += y;
    }
    int total = __shfl(x, 63);
    int base = 0;
    if (lane == 63) base = atomicAdd(gtotal, total);
    base = __shfl(base, 63);
    int excl = x - v;
    if (i < n) { rowstart[i] = base + excl; cursor[i] = base + excl; }
}

// ---------------- scatter edges into CSR with precomputed weight ----------------
__global__ void scatter_kernel(const int* __restrict__ ei, int* __restrict__ cursor,
                               const float* __restrict__ dinv,
                               int2* __restrict__ edges, int e) {
    int i = blockIdx.x * blockDim.x + threadIdx.x;
    if (i < e) {
        int d = ei[e + i];
        int s = ei[i];
        int pos = atomicAdd(&cursor[d], 1);
        float w = dinv[s] * dinv[d];
        edges[pos] = make_int2(s, __float_as_int(w));
    }
}

// ---------------- GCN propagation: FOUR nodes per wave (16 lanes, 16B each), --------
// 8-edge software pipeline. BN=true fuses relu(v*ca+cb) into the gather read path.
template <bool BN>
__global__ __launch_bounds__(256) void prop_kernel(
        const unsigned short* __restrict__ in, unsigned short* __restrict__ out,
        const float* __restrict__ coef,
        const float* __restrict__ dinv, const int* __restrict__ rowstart,
        const int* __restrict__ cnt, const int2* __restrict__ edges, int n) {
    int gw = (blockIdx.x * blockDim.x + threadIdx.x) >> 6;
    int lane = threadIdx.x & 63;
    int grp = lane >> 4;
    int hl = lane & 15;
    int node = gw * 4 + grp;
    bool act = node < n;
    int nd = act ? node : (n - 1);
    int c0 = hl * 8;                 // ushort offset; 16B per lane

    float ca[8], cb[8];
    if (BN) {
        float4 t0 = *reinterpret_cast<const float4*>(coef + c0);
        float4 t1 = *reinterpret_cast<const float4*>(coef + c0 + 4);
        float4 t2 = *reinterpret_cast<const float4*>(coef + 128 + c0);
        float4 t3 = *reinterpret_cast<const float4*>(coef + 128 + c0 + 4);
        ca[0] = t0.x; ca[1] = t0.y; ca[2] = t0.z; ca[3] = t0.w;
        ca[4] = t1.x; ca[5] = t1.y; ca[6] = t1.z; ca[7] = t1.w;
        cb[0] = t2.x; cb[1] = t2.y; cb[2] = t2.z; cb[3] = t2.w;
        cb[4] = t3.x; cb[5] = t3.y; cb[6] = t3.z; cb[7] = t3.w;
    }

    float di = dinv[nd];
    uint4 sp = *reinterpret_cast<const uint4*>(in + (size_t)nd * 128 + c0);
    float a[8];
    {
        unsigned int pk[4] = {sp.x, sp.y, sp.z, sp.w};
        float ws = di * di;
        #pragma unroll
        for (int q = 0; q < 4; ++q) {
            float lo = blo(pk[q]), hi = bhi(pk[q]);
            if (BN) {
                lo = fmaxf(fmaf(lo, ca[2 * q], cb[2 * q]), 0.f);
                hi = fmaxf(fmaf(hi, ca[2 * q + 1], cb[2 * q + 1]), 0.f);
            }
            a[2 * q] = lo * ws;
            a[2 * q + 1] = hi * ws;
        }
    }

    int beg = rowstart[nd];
    int len = cnt[nd];
    int m = max(len, __shfl_xor(len, 16));
    m = max(m, __shfl_xor(m, 32));
    int last = (len > 0) ? (beg + len - 1) : 0;   // edges[0] always valid (E >= 1)

    for (int t = 0; t < m; t += 8) {
        int2 e[8];
        #pragma unroll
        for (int j = 0; j < 8; ++j)
            e[j] = edges[min(beg + t + j, last)];
        uint4 u[8];
        #pragma unroll
        for (int j = 0; j < 8; ++j)
            u[j] = *reinterpret_cast<const uint4*>(in + (size_t)e[j].x * 128 + c0);
        float w[8];
        #pragma unroll
        for (int j = 0; j < 8; ++j)
            w[j] = (t + j < len) ? __int_as_float(e[j].y) : 0.f;
        #pragma unroll
        for (int j = 0; j < 8; ++j) {
            unsigned int pk[4] = {u[j].x, u[j].y, u[j].z, u[j].w};
            #pragma unroll
            for (int q = 0; q < 4; ++q) {
                float lo = blo(pk[q]), hi = bhi(pk[q]);
                if (BN) {
                    lo = fmaxf(fmaf(lo, ca[2 * q], cb[2 * q]), 0.f);
                    hi = fmaxf(fmaf(hi, ca[2 * q + 1], cb[2 * q + 1]), 0.f);
                }
                a[2 * q] = fmaf(lo, w[j], a[2 * q]);
                a[2 * q + 1] = fmaf(hi, w[j], a[2 * q + 1]);
            }
        }
    }

    if (act) {
        uint4 o;
        o.x = pack2(a[0], a[1]);
        o.y = pack2(a[2], a[3]);
        o.z = pack2(a[4], a[5]);
        o.w = pack2(a[6], a[7]);
        *reinterpret_cast<uint4*>(out + (size_t)node * 128 + c0) = o;
    }
}

// ---------------- MFMA GEMM: bf16 [n,128] @ [128,COLS] + b, per-block BN partials ----
template <int COLS, bool OUT_BF, bool STATS>
__global__ __launch_bounds__(256) void gemm_kernel(
        const unsigned short* __restrict__ A, const unsigned short* __restrict__ Bswz,
        const float* __restrict__ bias, void* __restrict__ out,
        float* __restrict__ statsP, int n) {
    constexpr int NT = COLS / 16;
    __shared__ unsigned short Blds[128 * COLS];
    __shared__ float s_sum[128];
    __shared__ float s_sq[128];

    int t = threadIdx.x;
    int w = t >> 6, l = t & 63;
    int lr = l & 15, lg = l >> 4;
    int row_base = blockIdx.x * 128 + w * 32;

    // A fragments first (longest-latency gathers in flight early)
    bf16x8 a[2][4];
    #pragma unroll
    for (int m = 0; m < 2; ++m) {
        int row = min(row_base + m * 16 + lr, n - 1);
        const unsigned short* ap = A + (size_t)row * 128 + lg * 8;
        #pragma unroll
        for (int kb = 0; kb < 4; ++kb)
            a[m][kb] = *reinterpret_cast<const bf16x8*>(ap + kb * 32);
    }

    // stage swizzled B linearly (conflict-free)
    constexpr int WORDS16 = 128 * COLS * 2 / 16;   // uint4 chunks
    for (int i = t; i < WORDS16; i += 256)
        reinterpret_cast<uint4*>(Blds)[i] = reinterpret_cast<const uint4*>(Bswz)[i];
    if (STATS) {
        if (t < 128) { s_sum[t] = 0.f; s_sq[t] = 0.f; }
    }

    f32x4 acc[2][NT];
    #pragma unroll
    for (int m = 0; m < 2; ++m)
        #pragma unroll
        for (int nn = 0; nn < NT; ++nn)
            acc[m][nn] = f32x4{0.f, 0.f, 0.f, 0.f};

    __syncthreads();

    #pragma unroll
    for (int kb = 0; kb < 4; ++kb) {
        bf16x8 b[NT];
        #pragma unroll
        for (int nn = 0; nn < NT; ++nn) {
            int c = nn * 16 + lr;
            int chunk = (kb * 4 + lg) ^ (c & 7);
            b[nn] = *reinterpret_cast<const bf16x8*>(
                        reinterpret_cast<const char*>(Blds) + c * 256 + chunk * 16);
        }
        #pragma unroll
        for (int m = 0; m < 2; ++m)
            #pragma unroll
            for (int nn = 0; nn < NT; ++nn)
                acc[m][nn] = __builtin_amdgcn_mfma_f32_16x16x32_bf16(a[m][kb], b[nn], acc[m][nn], 0, 0, 0);
    }

    // epilogue: D layout col = lr, row = lg*4 + q
    float ps[NT], pq[NT];
    #pragma unroll
    for (int nn = 0; nn < NT; ++nn) { ps[nn] = 0.f; pq[nn] = 0.f; }
    #pragma unroll
    for (int m = 0; m < 2; ++m) {
        #pragma unroll
        for (int nn = 0; nn < NT; ++nn) {
            int col = nn * 16 + lr;
            float bb = bias[col];
            #pragma unroll
            for (int q = 0; q < 4; ++q) {
                int row = row_base + m * 16 + lg * 4 + q;
                float v = acc[m][nn][q] + bb;
                if (row < n) {
                    if (OUT_BF)
                        reinterpret_cast<unsigned short*>(out)[(size_t)row * COLS + col] = f2b(v);
                    else
                        reinterpret_cast<float*>(out)[(size_t)row * COLS + col] = v;
                    if (STATS) { ps[nn] += v; pq[nn] += v * v; }
                }
            }
        }
    }

    if (STATS) {
        #pragma unroll
        for (int nn = 0; nn < NT; ++nn) {
            float s = ps[nn], q = pq[nn];
            s += __shfl_xor(s, 16); s += __shfl_xor(s, 32);
            q += __shfl_xor(q, 16); q += __shfl_xor(q, 32);
            if (lg == 0) {
                atomicAdd(&s_sum[nn * 16 + lr], s);   // 4 waves combine
                atomicAdd(&s_sq[nn * 16 + lr], q);
            }
        }
        __syncthreads();
        float* row = statsP + (size_t)blockIdx.x * 256;
        if (t < 128) row[t] = s_sum[t];
        else         row[t] = s_sq[t - 128];
    }
}

// ---------------- column reduce of per-block partials + BN coefficients -------------
__global__ void reduce_coef_kernel(const float* __restrict__ sp,
                                   const float* __restrict__ g, const float* __restrict__ be,
                                   float* __restrict__ coef, int nb, int n) {
    int c = blockIdx.x;          // 0..127
    float s = 0.f, q = 0.f;
    for (int b = threadIdx.x; b < nb; b += 256) {
        const float* row = sp + (size_t)b * 256;
        s += row[c];
        q += row[128 + c];
    }
    #pragma unroll
    for (int off = 32; off > 0; off >>= 1) {
        s += __shfl_xor(s, off);
        q += __shfl_xor(q, off);
    }
    __shared__ float ws4[4], wq4[4];
    int w = threadIdx.x >> 6;
    if ((threadIdx.x & 63) == 0) { ws4[w] = s; wq4[w] = q; }
    __syncthreads();
    if (threadIdx.x == 0) {
        float S = ws4[0] + ws4[1] + ws4[2] + ws4[3];
        float Q = wq4[0] + wq4[1] + wq4[2] + wq4[3];
        float inv_n = 1.0f / (float)n;
        float mean = S * inv_n;
        float var = Q * inv_n - mean * mean;
        float a = g[c] * rsqrtf(var + BN_EPS);
        coef[c] = a;
        coef[128 + c] = be[c] - mean * a;
    }
}

// ---------------- decode: TWO label edges per wave, 16B loads -----------------------
__global__ void decode_kernel(const unsigned short* __restrict__ emb, const int* __restrict__ lab,
                              float* __restrict__ r, int elab) {
    int wid = (blockIdx.x * blockDim.x + threadIdx.x) >> 6;
    int lane = threadIdx.x & 63;
    int half = lane >> 5;            // which of the two edges
    int ab = (lane >> 4) & 1;        // endpoint a or b
    int eidx = wid * 2 + half;
    bool act = eidx < elab;
    int ec = act ? eidx : 0;
    int row = ab ? lab[elab + ec] : lab[ec];
    int c0 = (lane & 15) * 8;
    uint4 u = *reinterpret_cast<const uint4*>(emb + (size_t)row * 128 + c0);
    uint4 o;
    o.x = __shfl_xor(u.x, 16);
    o.y = __shfl_xor(u.y, 16);
    o.z = __shfl_xor(u.z, 16);
    o.w = __shfl_xor(u.w, 16);
    float s = blo(u.x) * blo(o.x) + bhi(u.x) * bhi(o.x)
            + blo(u.y) * blo(o.y) + bhi(u.y) * bhi(o.y)
            + blo(u.z) * blo(o.z) + bhi(u.z) * bhi(o.z)
            + blo(u.w) * blo(o.w) + bhi(u.w) * bhi(o.w);
    #pragma unroll
    for (int off = 8; off > 0; off >>= 1) s += __shfl_xor(s, off);
    if ((lane & 31) == 0 && act) r[eidx] = 1.0f / (1.0f + expf(-s));
}

static inline char* carve(char*& p, size_t bytes) {
    char* r = p;
    p += (bytes + 255) & ~(size_t)255;
    return r;
}

extern "C" void kernel_launch(void* const* d_in, const int* in_sizes, int n_in,
                              void* d_out, int out_size, void* d_ws, size_t ws_size,
                              hipStream_t stream) {
    const float* x   = (const float*)d_in[0];
    const int*   ei  = (const int*)d_in[1];
    const int*   lab = (const int*)d_in[2];
    const float* W1 = (const float*)d_in[3],  *b1 = (const float*)d_in[4];
    const float* g1 = (const float*)d_in[5],  *be1 = (const float*)d_in[6];
    const float* W2 = (const float*)d_in[7],  *b2 = (const float*)d_in[8];
    const float* g2 = (const float*)d_in[9],  *be2 = (const float*)d_in[10];
    const float* W3 = (const float*)d_in[11], *b3 = (const float*)d_in[12];

    const int N = in_sizes[0] / 128;
    const int E = in_sizes[1] / 2;
    const int ELAB = in_sizes[2] / 2;

    int gG = (N + 127) / 128;

    char* p = (char*)d_ws;
    int*   count    = (int*)carve(p, (size_t)N * 4);
    int*   cursor   = (int*)carve(p, (size_t)N * 4);
    int*   rowstart = (int*)carve(p, (size_t)N * 4);
    float* dinv     = (float*)carve(p, (size_t)N * 4);
    int2*  edges    = (int2*)carve(p, (size_t)E * 8);
    int*   gtotal   = (int*)carve(p, 256);
    float* statsP   = (float*)carve(p, (size_t)gG * 256 * 4);
    float* coef1    = (float*)carve(p, 256 * 4);
    float* coef2    = (float*)carve(p, 256 * 4);
    unsigned short* Wt1 = (unsigned short*)carve(p, 128 * 128 * 2);
    unsigned short* Wt2 = (unsigned short*)carve(p, 128 * 128 * 2);
    unsigned short* Wt3 = (unsigned short*)carve(p, 128 * 64 * 2);
    unsigned short* xb  = (unsigned short*)carve(p, (size_t)N * 128 * 2);
    unsigned short* bA  = (unsigned short*)carve(p, (size_t)N * 128 * 2);
    unsigned short* bB  = (unsigned short*)carve(p, (size_t)N * 128 * 2);

    dim3 blk(256);
    int gN   = (N + 255) / 256;
    int gE   = (E + 255) / 256;
    int nWP  = (N + 3) / 4;                  // prop waves (4 nodes each)
    int gWN  = (nWP * 64 + 255) / 256;
    int nWL  = (ELAB + 1) / 2;               // decode waves (2 edges each)
    int gWL  = (nWL * 64 + 255) / 256;
    int g4   = (N * 32 + 255) / 256;

    // fused prep (cvt + zero count + wprep), then CSR build
    prep_kernel<<<g4, blk, 0, stream>>>(x, xb, N * 32, count, gtotal, N,
                                        W1, Wt1, W2, Wt2, W3, Wt3);
    count_kernel<<<gE, blk, 0, stream>>>(ei, count, E);
    offsets_kernel<<<gN, blk, 0, stream>>>(count, dinv, rowstart, cursor, gtotal, N);
    scatter_kernel<<<gE, blk, 0, stream>>>(ei, cursor, dinv, edges, E);

    // layer 1
    prop_kernel<false><<<gWN, blk, 0, stream>>>(xb, bA, nullptr, dinv, rowstart, count, edges, N);
    gemm_kernel<128, true, true><<<gG, blk, 0, stream>>>(bA, Wt1, b1, bB, statsP, N);
    reduce_coef_kernel<<<128, blk, 0, stream>>>(statsP, g1, be1, coef1, gG, N);

    // layer 2 (BN+ReLU of layer 1 fused into prop's read path)
    prop_kernel<true><<<gWN, blk, 0, stream>>>(bB, bA, coef1, dinv, rowstart, count, edges, N);
    gemm_kernel<128, true, true><<<gG, blk, 0, stream>>>(bA, Wt2, b2, bB, statsP, N);
    reduce_coef_kernel<<<128, blk, 0, stream>>>(statsP, g2, be2, coef2, gG, N);

    // layer 3: emb = prop(relu(bn(h2))); x_out = emb @ W3 + b3; r = sigmoid(<emb,emb>)
    prop_kernel<true><<<gWN, blk, 0, stream>>>(bB, bA, coef2, dinv, rowstart, count, edges, N);
    gemm_kernel<64, false, false><<<gG, blk, 0, stream>>>(bA, Wt3, b3, (float*)d_out, nullptr, N);
    decode_kernel<<<gWL, blk, 0, stream>>>(bA, lab, (float*)d_out + (size_t)N * 64, ELAB);
}